// Round 6
// baseline (5623.843 us; speedup 1.0000x reference)
//
#include <hip/hip_runtime.h>
#include <hip/hip_bf16.h>
#include <math.h>

#define BH 64
#define NSEQ 8192
#define DHEAD 64
#define M 128
#define LGRP 64
#define NC 8
#define CHUNK (NSEQ / NC)   // 1024
#define NSWEEP 10
#define NROUND 127
#define RCOND 1.52587890625e-4   // 10 * 128 * eps_f32  (jax f32 pinv rtol)

// ---------------- Kernel A: landmarks (f64 pooling, q scaled by 1/8) ----------------
__global__ __launch_bounds__(64) void lm_kernel(const float* __restrict__ q,
                                                const float* __restrict__ k,
                                                double* __restrict__ ql64,
                                                double* __restrict__ kl64,
                                                float* __restrict__ qlf32,
                                                float* __restrict__ klf32) {
    int idx = blockIdx.x;            // 0..16383
    int tensor = idx >> 13;          // 0 = q, 1 = k
    int g = idx & 8191;
    int head = g >> 7, m = g & 127;
    int d = threadIdx.x;
    const float* src = tensor ? k : q;
    const float* base = src + ((size_t)head * NSEQ + (size_t)m * LGRP) * DHEAD + d;
    double s = 0.0;
    #pragma unroll 8
    for (int r = 0; r < LGRP; ++r) s += (double)base[(size_t)r * DHEAD];
    s *= (1.0 / LGRP);
    if (!tensor) s *= 0.125;         // q / sqrt(64)
    size_t o = (size_t)head * M * DHEAD + (size_t)m * DHEAD + d;
    if (!tensor) { ql64[o] = s; qlf32[o] = (float)s; }
    else         { kl64[o] = s; klf32[o] = (float)s; }
}

// ---------------- Kernel B: S = softmax(ql @ kl^T) f64, col-major; also writes Gg copy ----
__global__ __launch_bounds__(512) void s_kernel(const double* __restrict__ ql64,
                                                const double* __restrict__ kl64,
                                                double* __restrict__ Sg,
                                                double* __restrict__ Gg,
                                                int* __restrict__ conv) {
    extern __shared__ double lds[];      // qlds[8192] | klds[8192]  (128 KB)
    double* qlds = lds;
    double* klds = lds + M * DHEAD;
    int head = blockIdx.x;
    int t = threadIdx.x;
    if (t == 0) conv[head] = 0;          // reset per call (harness doesn't re-poison)
    const double2* qg = (const double2*)(ql64 + (size_t)head * M * DHEAD);
    const double2* kg = (const double2*)(kl64 + (size_t)head * M * DHEAD);
    for (int e = t; e < M * DHEAD / 2; e += 512) {
        ((double2*)qlds)[e] = qg[e];
        ((double2*)klds)[e] = kg[e];
    }
    __syncthreads();
    int tr = t >> 4, tc = t & 15;        // rows 4tr..+4, cols 8tc..+8
    double acc[4][8];
    #pragma unroll
    for (int i = 0; i < 4; ++i)
        #pragma unroll
        for (int j = 0; j < 8; ++j) acc[i][j] = 0.0;
    for (int dc = 0; dc < DHEAD; dc += 4) {
        double qreg[4][4], kreg[8][4];
        #pragma unroll
        for (int i = 0; i < 4; ++i)
            #pragma unroll
            for (int d = 0; d < 4; ++d) qreg[i][d] = qlds[(4 * tr + i) * DHEAD + dc + d];
        #pragma unroll
        for (int j = 0; j < 8; ++j)
            #pragma unroll
            for (int d = 0; d < 4; ++d) kreg[j][d] = klds[(8 * tc + j) * DHEAD + dc + d];
        #pragma unroll
        for (int i = 0; i < 4; ++i)
            #pragma unroll
            for (int j = 0; j < 8; ++j)
                #pragma unroll
                for (int d = 0; d < 4; ++d) acc[i][j] += qreg[i][d] * kreg[j][d];
    }
    double* So = Sg + (size_t)head * M * M;
    double* Go = Gg + (size_t)head * M * M;
    #pragma unroll
    for (int i = 0; i < 4; ++i) {
        double mx = acc[i][0];
        #pragma unroll
        for (int j = 1; j < 8; ++j) mx = fmax(mx, acc[i][j]);
        mx = fmax(mx, __shfl_xor(mx, 1));
        mx = fmax(mx, __shfl_xor(mx, 2));
        mx = fmax(mx, __shfl_xor(mx, 4));
        mx = fmax(mx, __shfl_xor(mx, 8));
        double sum = 0.0;
        #pragma unroll
        for (int j = 0; j < 8; ++j) { acc[i][j] = exp(acc[i][j] - mx); sum += acc[i][j]; }
        sum += __shfl_xor(sum, 1); sum += __shfl_xor(sum, 2);
        sum += __shfl_xor(sum, 4); sum += __shfl_xor(sum, 8);
        double inv = 1.0 / sum;
        #pragma unroll
        for (int j = 0; j < 8; ++j) {
            double vv = acc[i][j] * inv;
            size_t oo = (size_t)(8 * tc + j) * M + 4 * tr + i;   // col-major
            So[oo] = vv;
            Go[oo] = vv;
        }
    }
}

// ---------------- Kernel C: ONE Jacobi sweep (127 rounds) on Gg, LDS-resident -------------
// [col][130] f64 layout: column stride 1040 B -> bank offset 4*col; consecutive columns per
// wave -> 2-way max (free). Contiguous ds_read_b128/write_b128 (8 per column per lane).
__global__ __launch_bounds__(512) void jsweep_kernel(double* __restrict__ Gg,
                                                     int* __restrict__ conv) {
    __shared__ double G[M * 130];    // 133,120 B
    __shared__ int anyrot;
    int head = blockIdx.x;
    if (conv[head]) return;          // converged in an earlier sweep
    int t = threadIdx.x;
    double* Gh = Gg + (size_t)head * M * M;
    double2* G2 = (double2*)G;
    double2* S2 = (double2*)Gh;
    for (int e = t; e < M * 64; e += 512) {
        int col = e >> 6, rp = e & 63;
        G2[col * 65 + rp] = S2[e];
    }
    if (t == 0) anyrot = 0;
    __syncthreads();
    int grp = t >> 3, s = t & 7;     // 64 pair-groups x 8 lanes
    for (int r = 0; r < NROUND; ++r) {
        int ca, cb;
        if (grp == 0) { ca = 127; cb = r; }
        else { ca = (r + grp) % 127; cb = (r + 127 - grp) % 127; }
        double2* gA = (double2*)(G + ca * 130);
        double2* gB = (double2*)(G + cb * 130);
        double2 va[8], vb[8];
        #pragma unroll
        for (int j = 0; j < 8; ++j) va[j] = gA[j * 8 + s];
        #pragma unroll
        for (int j = 0; j < 8; ++j) vb[j] = gB[j * 8 + s];
        double a = 0.0, b = 0.0, c = 0.0;
        #pragma unroll
        for (int j = 0; j < 8; ++j) {
            a += va[j].x * va[j].x + va[j].y * va[j].y;
            b += vb[j].x * vb[j].x + vb[j].y * vb[j].y;
            c += va[j].x * vb[j].x + va[j].y * vb[j].y;
        }
        a += __shfl_xor(a, 1); b += __shfl_xor(b, 1); c += __shfl_xor(c, 1);
        a += __shfl_xor(a, 2); b += __shfl_xor(b, 2); c += __shfl_xor(c, 2);
        a += __shfl_xor(a, 4); b += __shfl_xor(b, 4); c += __shfl_xor(c, 4);
        if (c * c > 1e-24 * a * b) {          // skip sub-1e-12 angles (no LDS writes)
            if (c * c > 1e-18 * a * b) anyrot = 1;   // angle > 1e-9: not converged
            double zeta = (b - a) / (2.0 * c);
            double tt = (zeta >= 0.0 ? 1.0 : -1.0) / (fabs(zeta) + sqrt(1.0 + zeta * zeta));
            double cs = 1.0 / sqrt(1.0 + tt * tt);
            double sn = cs * tt;
            #pragma unroll
            for (int j = 0; j < 8; ++j) {
                double nax = cs * va[j].x - sn * vb[j].x;
                double nay = cs * va[j].y - sn * vb[j].y;
                double nbx = sn * va[j].x + cs * vb[j].x;
                double nby = sn * va[j].y + cs * vb[j].y;
                gA[j * 8 + s] = make_double2(nax, nay);
                gB[j * 8 + s] = make_double2(nbx, nby);
            }
        }
        __syncthreads();
    }
    for (int e = t; e < M * 64; e += 512) {
        int col = e >> 6, rp = e & 63;
        S2[e] = G2[col * 65 + rp];
    }
    if (t == 0 && !anyrot) conv[head] = 1;
}

// ---------------- Kernel D: truncation + W = u / sigma^2 from converged G -----------------
__global__ __launch_bounds__(512) void wfinal_kernel(const double* __restrict__ Gg,
                                                     double* __restrict__ Wcol) {
    __shared__ double norms2[M];
    __shared__ double maxn2;
    int head = blockIdx.x;
    int t = threadIdx.x;
    const double* Gh = Gg + (size_t)head * M * M;
    {
        int col = t >> 2, qd = t & 3;
        double s = 0.0;
        #pragma unroll 8
        for (int x = qd * 32; x < qd * 32 + 32; ++x) { double v = Gh[col * 128 + x]; s += v * v; }
        s += __shfl_xor(s, 1); s += __shfl_xor(s, 2);
        if (qd == 0) norms2[col] = s;
    }
    __syncthreads();
    if (t < 64) {
        double mm = fmax(norms2[t], norms2[t + 64]);
        for (int off = 32; off > 0; off >>= 1) mm = fmax(mm, __shfl_down(mm, off));
        if (t == 0) maxn2 = mm;
    }
    __syncthreads();
    double cut2 = maxn2 * (RCOND * RCOND);
    for (int e = t; e < M * M; e += 512) {
        int cc = e >> 7;
        double n2 = norms2[cc];
        Wcol[(size_t)head * M * M + e] = (n2 > cut2) ? Gh[e] / n2 : 0.0;
    }
}

// ---------------- Kernel E: partial B@v -- f32 dot/exp + blocked f64 flush ----------------
__global__ __launch_bounds__(256) void bv_kernel(const float* __restrict__ k,
                                                 const float* __restrict__ v,
                                                 const float* __restrict__ qlf32,
                                                 double* __restrict__ numd,
                                                 double* __restrict__ dend) {
    int head = blockIdx.x >> 3;   // NC = 8
    int chunk = blockIdx.x & 7;
    int t = threadIdx.x;
    int m = t >> 1, h = t & 1;
    float ql[32];
    const float* qb = qlf32 + ((size_t)head * M + m) * DHEAD + h * 32;
    #pragma unroll
    for (int d = 0; d < 32; ++d) ql[d] = qb[d];
    float acc32[32]; double acc64[32];
    #pragma unroll
    for (int d = 0; d < 32; ++d) { acc32[d] = 0.f; acc64[d] = 0.0; }
    float dacc32 = 0.f; double dacc64 = 0.0;
    const float* kb = k + ((size_t)head * NSEQ + (size_t)chunk * CHUNK) * DHEAD + h * 32;
    const float* vb = v + ((size_t)head * NSEQ + (size_t)chunk * CHUNK) * DHEAD + h * 32;
    for (int key = 0; key < CHUNK; ++key) {
        const float4* kr = (const float4*)(kb + (size_t)key * DHEAD);
        float z = 0.f;
        #pragma unroll
        for (int c = 0; c < 8; ++c) {
            float4 kk = kr[c];
            z += ql[4 * c] * kk.x + ql[4 * c + 1] * kk.y + ql[4 * c + 2] * kk.z + ql[4 * c + 3] * kk.w;
        }
        z += __shfl_xor(z, 1);
        float e = __expf(z);
        dacc32 += e;
        const float4* vr = (const float4*)(vb + (size_t)key * DHEAD);
        #pragma unroll
        for (int c = 0; c < 8; ++c) {
            float4 vv = vr[c];
            acc32[4 * c]     += e * vv.x;
            acc32[4 * c + 1] += e * vv.y;
            acc32[4 * c + 2] += e * vv.z;
            acc32[4 * c + 3] += e * vv.w;
        }
        if (((key + 1) & 127) == 0) {
            #pragma unroll
            for (int d = 0; d < 32; ++d) { acc64[d] += (double)acc32[d]; acc32[d] = 0.f; }
            dacc64 += (double)dacc32; dacc32 = 0.f;
        }
    }
    size_t ob = (((size_t)head * NC + chunk) * M + m) * DHEAD + h * 32;
    #pragma unroll
    for (int d = 0; d < 32; ++d) numd[ob + d] = acc64[d];
    if (h == 0) dend[((size_t)head * NC + chunk) * M + m] = dacc64;
}

// ---------------- Kernel F: fused  Bv reduce -> W^T -> W -> S^T  (f64, ABv out f32) ----
__global__ __launch_bounds__(512) void apply_kernel(const double* __restrict__ numd,
                                                    const double* __restrict__ dend,
                                                    const double* __restrict__ Wcol,
                                                    const double* __restrict__ Sg,
                                                    float* __restrict__ ABvf32) {
    extern __shared__ double lds[];
    double* A_ = lds;                 // [128][66]
    double* B_ = lds + M * 66;
    __shared__ double dsum[M];
    int head = blockIdx.x;
    int t = threadIdx.x;
    if (t < M) {
        double s = 0.0;
        #pragma unroll
        for (int c = 0; c < NC; ++c) s += dend[((size_t)head * NC + c) * M + t];
        dsum[t] = s;
    }
    __syncthreads();
    for (int e = t; e < M * DHEAD; e += 512) {
        int mm = e >> 6;
        double s = 0.0;
        #pragma unroll
        for (int c = 0; c < NC; ++c) s += numd[((size_t)head * NC + c) * (M * DHEAD) + e];
        A_[mm * 66 + (e & 63)] = s / dsum[mm];
    }
    __syncthreads();
    int i = t >> 3, qd = t & 7;
    const double* Wb = Wcol + (size_t)head * M * M;
    const double* Sb = Sg + (size_t)head * M * M;
    {   // stage 1: B = W^T A
        double a0[8], a1[8];
        #pragma unroll
        for (int d = 0; d < 8; ++d) { a0[d] = 0.0; a1[d] = 0.0; }
        for (int r = 0; r < M; ++r) {
            double m0 = Wb[(size_t)i * M + r];
            double m1 = Wb[(size_t)(i + 64) * M + r];
            #pragma unroll
            for (int d = 0; d < 8; ++d) {
                double xv = A_[r * 66 + qd * 8 + d];
                a0[d] += m0 * xv; a1[d] += m1 * xv;
            }
        }
        #pragma unroll
        for (int d = 0; d < 8; ++d) {
            B_[i * 66 + qd * 8 + d] = a0[d];
            B_[(i + 64) * 66 + qd * 8 + d] = a1[d];
        }
    }
    __syncthreads();
    {   // stage 2: A = W B
        double a0[8], a1[8];
        #pragma unroll
        for (int d = 0; d < 8; ++d) { a0[d] = 0.0; a1[d] = 0.0; }
        for (int r = 0; r < M; ++r) {
            double m0 = Wb[(size_t)r * M + i];
            double m1 = Wb[(size_t)r * M + i + 64];
            #pragma unroll
            for (int d = 0; d < 8; ++d) {
                double xv = B_[r * 66 + qd * 8 + d];
                a0[d] += m0 * xv; a1[d] += m1 * xv;
            }
        }
        #pragma unroll
        for (int d = 0; d < 8; ++d) {
            A_[i * 66 + qd * 8 + d] = a0[d];
            A_[(i + 64) * 66 + qd * 8 + d] = a1[d];
        }
    }
    __syncthreads();
    {   // stage 3: ABv = S^T A
        double a0[8], a1[8];
        #pragma unroll
        for (int d = 0; d < 8; ++d) { a0[d] = 0.0; a1[d] = 0.0; }
        for (int r = 0; r < M; ++r) {
            double m0 = Sb[(size_t)i * M + r];
            double m1 = Sb[(size_t)(i + 64) * M + r];
            #pragma unroll
            for (int d = 0; d < 8; ++d) {
                double xv = A_[r * 66 + qd * 8 + d];
                a0[d] += m0 * xv; a1[d] += m1 * xv;
            }
        }
        float* ob = ABvf32 + (size_t)head * M * DHEAD;
        #pragma unroll
        for (int d = 0; d < 8; ++d) {
            ob[i * DHEAD + qd * 8 + d] = (float)a0[d];
            ob[(i + 64) * DHEAD + qd * 8 + d] = (float)a1[d];
        }
    }
}

// ---------------- Kernel G: out = softmax(q @ kl^T) @ ABv  (f32, 2-row tiling) --------
__global__ __launch_bounds__(512) void out_kernel(const float* __restrict__ q,
                                                  const float* __restrict__ klf32,
                                                  const float* __restrict__ ABvf32,
                                                  float* __restrict__ out) {
    __shared__ float kls[M * DHEAD];
    __shared__ float avs[M * DHEAD];
    int head = blockIdx.x >> 4;
    int tile = blockIdx.x & 15;
    int t = threadIdx.x;
    for (int e = t; e < M * DHEAD; e += 512) {
        kls[e] = klf32[(size_t)head * M * DHEAD + e];
        avs[e] = ABvf32[(size_t)head * M * DHEAD + e];
    }
    __syncthreads();
    int rl = t >> 1, h = t & 1;
    size_t row0 = (size_t)head * NSEQ + (size_t)tile * 512 + rl;
    size_t row1 = row0 + 256;
    const float4* qr0 = (const float4*)(q + row0 * DHEAD + h * 32);
    const float4* qr1 = (const float4*)(q + row1 * DHEAD + h * 32);
    float4 qa[8], qb[8];
    #pragma unroll
    for (int c = 0; c < 8; ++c) {
        float4 x = qr0[c];
        x.x *= 0.125f; x.y *= 0.125f; x.z *= 0.125f; x.w *= 0.125f;
        qa[c] = x;
        float4 y = qr1[c];
        y.x *= 0.125f; y.y *= 0.125f; y.z *= 0.125f; y.w *= 0.125f;
        qb[c] = y;
    }
    float acc0[32], acc1[32];
    #pragma unroll
    for (int d = 0; d < 32; ++d) { acc0[d] = 0.f; acc1[d] = 0.f; }
    float d0 = 0.f, d1 = 0.f;
    for (int mm = 0; mm < M; ++mm) {
        const float4* kr = (const float4*)(kls + mm * DHEAD + h * 32);
        float z0 = 0.f, z1 = 0.f;
        #pragma unroll
        for (int c = 0; c < 8; ++c) {
            float4 kk = kr[c];
            z0 += qa[c].x * kk.x + qa[c].y * kk.y + qa[c].z * kk.z + qa[c].w * kk.w;
            z1 += qb[c].x * kk.x + qb[c].y * kk.y + qb[c].z * kk.z + qb[c].w * kk.w;
        }
        z0 += __shfl_xor(z0, 1);
        z1 += __shfl_xor(z1, 1);
        float e0 = __expf(z0), e1 = __expf(z1);
        d0 += e0; d1 += e1;
        const float4* ar = (const float4*)(avs + mm * DHEAD + h * 32);
        #pragma unroll
        for (int c = 0; c < 8; ++c) {
            float4 av = ar[c];
            acc0[4 * c]     += e0 * av.x; acc0[4 * c + 1] += e0 * av.y;
            acc0[4 * c + 2] += e0 * av.z; acc0[4 * c + 3] += e0 * av.w;
            acc1[4 * c]     += e1 * av.x; acc1[4 * c + 1] += e1 * av.y;
            acc1[4 * c + 2] += e1 * av.z; acc1[4 * c + 3] += e1 * av.w;
        }
    }
    float i0 = 1.f / d0, i1 = 1.f / d1;
    float* o0 = out + row0 * DHEAD + h * 32;
    float* o1 = out + row1 * DHEAD + h * 32;
    #pragma unroll
    for (int d = 0; d < 32; ++d) { o0[d] = acc0[d] * i0; o1[d] = acc1[d] * i1; }
}

extern "C" void kernel_launch(void* const* d_in, const int* in_sizes, int n_in,
                              void* d_out, int out_size, void* d_ws, size_t ws_size,
                              hipStream_t stream) {
    const float* q = (const float*)d_in[0];
    const float* k = (const float*)d_in[1];
    const float* v = (const float*)d_in[2];
    float* out = (float*)d_out;
    char* ws = (char*)d_ws;
    // ws map (<= 57,147,392 B). Liveness-based aliasing:
    //   [0,8M):   ql64|kl64 (die after s_kernel), then numd (bv -> apply)
    //   [8,16M):  Gg (s_kernel -> wfinal), then numd
    //   [16M+..): conv (s_kernel -> jsweep; dead before bv), then numd
    double* ql64  = (double*)(ws + 0);            //  4 MB
    double* kl64  = (double*)(ws + 4194304);      //  4 MB
    double* Gg    = (double*)(ws + 8388608);      //  8 MB (Jacobi working copy)
    int*    conv  = (int*)(ws + 16777216);        //  256 B
    double* numd  = (double*)(ws + 0);            // 32 MB (after wfinal)
    double* dend  = (double*)(ws + 33554432);     //  512 KB
    float*  qlf32 = (float*)(ws + 34078720);      //  2 MB
    float*  klf32 = (float*)(ws + 36175872);      //  2 MB
    double* Sg    = (double*)(ws + 38273024);     //  8 MB (S col-major, survives to apply)
    double* Wcol  = (double*)(ws + 46661632);     //  8 MB
    float*  ABvf32= (float*)(ws + 55050240);      //  2 MB

    lm_kernel<<<16384, 64, 0, stream>>>(q, k, ql64, kl64, qlf32, klf32);
    s_kernel<<<BH, 512, 2 * M * DHEAD * 8, stream>>>(ql64, kl64, Sg, Gg, conv);
    for (int sw = 0; sw < NSWEEP; ++sw)
        jsweep_kernel<<<BH, 512, 0, stream>>>(Gg, conv);
    wfinal_kernel<<<BH, 512, 0, stream>>>(Gg, Wcol);
    bv_kernel<<<BH * NC, 256, 0, stream>>>(k, v, qlf32, numd, dend);
    apply_kernel<<<BH, 512, 2 * M * 66 * 8, stream>>>(numd, dend, Wcol, Sg, ABvf32);
    out_kernel<<<BH * 16, 512, 0, stream>>>(q, klf32, ABvf32, out);
}

// Round 7
// 3236.183 us; speedup vs baseline: 1.7378x; 1.7378x over previous
//
#include <hip/hip_runtime.h>
#include <hip/hip_bf16.h>
#include <math.h>

#define BH 64
#define NSEQ 8192
#define DHEAD 64
#define M 128
#define LGRP 64
#define NCB 4
#define KPB (NSEQ / NCB)    // 2048 keys per bv block
#define TILE 64             // keys per LDS tile
#define NTILE (KPB / TILE)  // 32
#define NSWEEP 10
#define NROUND 127
#define RCOND 1.52587890625e-4   // 10 * 128 * eps_f32 (jax f32 pinv rtol)

// ---------------- Kernel A: landmarks (f64 pooling, q scaled by 1/8) ----------------
__global__ __launch_bounds__(64) void lm_kernel(const float* __restrict__ q,
                                                const float* __restrict__ k,
                                                double* __restrict__ ql64,
                                                double* __restrict__ kl64,
                                                float* __restrict__ qlf32,
                                                float* __restrict__ klf32) {
    int idx = blockIdx.x;            // 0..16383
    int tensor = idx >> 13;          // 0 = q, 1 = k
    int g = idx & 8191;
    int head = g >> 7, m = g & 127;
    int d = threadIdx.x;
    const float* src = tensor ? k : q;
    const float* base = src + ((size_t)head * NSEQ + (size_t)m * LGRP) * DHEAD + d;
    double s = 0.0;
    #pragma unroll 8
    for (int r = 0; r < LGRP; ++r) s += (double)base[(size_t)r * DHEAD];
    s *= (1.0 / LGRP);
    if (!tensor) s *= 0.125;         // q / sqrt(64)
    size_t o = (size_t)head * M * DHEAD + (size_t)m * DHEAD + d;
    if (!tensor) { ql64[o] = s; qlf32[o] = (float)s; }
    else         { kl64[o] = s; klf32[o] = (float)s; }
}

// ---------------- Kernel B: S = softmax(ql @ kl^T) f64, stored COLUMN-major ----------------
__global__ __launch_bounds__(512) void s_kernel(const double* __restrict__ ql64,
                                                const double* __restrict__ kl64,
                                                double* __restrict__ Sg) {
    extern __shared__ double lds[];      // qlds[8192] | klds[8192]
    double* qlds = lds;
    double* klds = lds + M * DHEAD;
    int head = blockIdx.x;
    int t = threadIdx.x;
    const double2* qg = (const double2*)(ql64 + (size_t)head * M * DHEAD);
    const double2* kg = (const double2*)(kl64 + (size_t)head * M * DHEAD);
    for (int e = t; e < M * DHEAD / 2; e += 512) {
        ((double2*)qlds)[e] = qg[e];
        ((double2*)klds)[e] = kg[e];
    }
    __syncthreads();
    int tr = t >> 4, tc = t & 15;
    double acc[4][8];
    #pragma unroll
    for (int i = 0; i < 4; ++i)
        #pragma unroll
        for (int j = 0; j < 8; ++j) acc[i][j] = 0.0;
    for (int dc = 0; dc < DHEAD; dc += 4) {
        double qreg[4][4], kreg[8][4];
        #pragma unroll
        for (int i = 0; i < 4; ++i)
            #pragma unroll
            for (int d = 0; d < 4; ++d) qreg[i][d] = qlds[(4 * tr + i) * DHEAD + dc + d];
        #pragma unroll
        for (int j = 0; j < 8; ++j)
            #pragma unroll
            for (int d = 0; d < 4; ++d) kreg[j][d] = klds[(8 * tc + j) * DHEAD + dc + d];
        #pragma unroll
        for (int i = 0; i < 4; ++i)
            #pragma unroll
            for (int j = 0; j < 8; ++j)
                #pragma unroll
                for (int d = 0; d < 4; ++d) acc[i][j] += qreg[i][d] * kreg[j][d];
    }
    double* So = Sg + (size_t)head * M * M;
    #pragma unroll
    for (int i = 0; i < 4; ++i) {
        double mx = acc[i][0];
        #pragma unroll
        for (int j = 1; j < 8; ++j) mx = fmax(mx, acc[i][j]);
        mx = fmax(mx, __shfl_xor(mx, 1));
        mx = fmax(mx, __shfl_xor(mx, 2));
        mx = fmax(mx, __shfl_xor(mx, 4));
        mx = fmax(mx, __shfl_xor(mx, 8));
        double sum = 0.0;
        #pragma unroll
        for (int j = 0; j < 8; ++j) { acc[i][j] = exp(acc[i][j] - mx); sum += acc[i][j]; }
        sum += __shfl_xor(sum, 1); sum += __shfl_xor(sum, 2);
        sum += __shfl_xor(sum, 4); sum += __shfl_xor(sum, 8);
        double inv = 1.0 / sum;
        #pragma unroll
        for (int j = 0; j < 8; ++j)
            So[(size_t)(8 * tc + j) * M + 4 * tr + i] = acc[i][j] * inv;   // col-major
    }
}

// ---------------- Fused: Jacobi SVD + Wcol (blocks 0..63)  ||  B@v GEMM (blocks 64..319) ----
// Jacobi: LDS-resident [col][130] f64, cached column norms (c-dot only, analytic norm
// update), both-junk pair skip, kept-column convergence early exit, inline W output.
// bv: per 2048-key chunk: 32 x {stage K/V 64-key tile -> Z=exp(QL*K^T) in LDS -> acc += E*V}.
__global__ __launch_bounds__(512) void fused_kernel(const double* __restrict__ Sg,
                                                    double* __restrict__ Wcol,
                                                    const float* __restrict__ k,
                                                    const float* __restrict__ v,
                                                    const float* __restrict__ qlf32,
                                                    double* __restrict__ numd,
                                                    double* __restrict__ dend) {
    extern __shared__ double ldsd[];     // 133,120 B shared by both paths
    __shared__ double norms2[M];
    __shared__ double maxn2s;
    __shared__ int anyrot, done;
    int t = threadIdx.x;

    if (blockIdx.x < BH) {
        // ======================= Jacobi =======================
        int head = blockIdx.x;
        double* G = ldsd;                // [128][130]
        const double2* Sh2 = (const double2*)(Sg + (size_t)head * M * M);
        double2* G2 = (double2*)G;
        for (int e = t; e < M * 64; e += 512) {
            int col = e >> 6, rp = e & 63;
            G2[col * 65 + rp] = Sh2[e];
        }
        __syncthreads();
        {   // initial norms^2
            int col = t >> 2, qd = t & 3;
            double s = 0.0;
            #pragma unroll 8
            for (int x = qd * 32; x < qd * 32 + 32; ++x) { double vv = G[col * 130 + x]; s += vv * vv; }
            s += __shfl_xor(s, 1); s += __shfl_xor(s, 2);
            if (qd == 0) norms2[col] = s;
        }
        if (t == 0) { anyrot = 1; done = 0; }
        __syncthreads();
        int grp = t >> 3, s8 = t & 7;
        for (int sweep = 0; sweep < NSWEEP; ++sweep) {
            if (t < 64) {
                double mm = fmax(norms2[t], norms2[t + 64]);
                for (int off = 32; off > 0; off >>= 1) mm = fmax(mm, __shfl_down(mm, off));
                if (t == 0) {
                    maxn2s = mm;
                    done = (sweep > 0 && anyrot == 0);
                    anyrot = 0;
                }
            }
            __syncthreads();
            if (done) break;
            double kc = maxn2s * (RCOND * RCOND);   // kept-column threshold on norm^2
            double sc = kc * (1.0 / 4096.0);        // both-below => pure junk pair, skip
            for (int r = 0; r < NROUND; ++r) {
                int ca, cb;
                if (grp == 0) { ca = 127; cb = r; }
                else { ca = (r + grp) % 127; cb = (r + 127 - grp) % 127; }
                double na = norms2[ca], nb = norms2[cb];
                if (!(na < sc && nb < sc)) {
                    double2* gA = (double2*)(G + ca * 130);
                    double2* gB = (double2*)(G + cb * 130);
                    double2 va[8], vb[8];
                    #pragma unroll
                    for (int j = 0; j < 8; ++j) va[j] = gA[j * 8 + s8];
                    #pragma unroll
                    for (int j = 0; j < 8; ++j) vb[j] = gB[j * 8 + s8];
                    double c = 0.0;
                    #pragma unroll
                    for (int j = 0; j < 8; ++j) c += va[j].x * vb[j].x + va[j].y * vb[j].y;
                    c += __shfl_xor(c, 1); c += __shfl_xor(c, 2); c += __shfl_xor(c, 4);
                    if (c * c > 1e-24 * na * nb) {
                        if ((na > kc || nb > kc) && c * c > 1e-18 * na * nb) anyrot = 1;
                        double zeta = (nb - na) / (2.0 * c);
                        double tt = (zeta >= 0.0 ? 1.0 : -1.0) / (fabs(zeta) + sqrt(1.0 + zeta * zeta));
                        double cs = 1.0 / sqrt(1.0 + tt * tt);
                        double sn = cs * tt;
                        #pragma unroll
                        for (int j = 0; j < 8; ++j) {
                            double nax = cs * va[j].x - sn * vb[j].x;
                            double nay = cs * va[j].y - sn * vb[j].y;
                            double nbx = sn * va[j].x + cs * vb[j].x;
                            double nby = sn * va[j].y + cs * vb[j].y;
                            gA[j * 8 + s8] = make_double2(nax, nay);
                            gB[j * 8 + s8] = make_double2(nbx, nby);
                        }
                        if (s8 == 0) {
                            norms2[ca] = fmax(na - tt * c, 0.0);
                            norms2[cb] = nb + tt * c;
                        }
                    }
                }
                __syncthreads();
            }
        }
        // exact norms + truncation + W = u / sigma^2
        {
            int col = t >> 2, qd = t & 3;
            double s = 0.0;
            #pragma unroll 8
            for (int x = qd * 32; x < qd * 32 + 32; ++x) { double vv = G[col * 130 + x]; s += vv * vv; }
            s += __shfl_xor(s, 1); s += __shfl_xor(s, 2);
            if (qd == 0) norms2[col] = s;
        }
        __syncthreads();
        if (t < 64) {
            double mm = fmax(norms2[t], norms2[t + 64]);
            for (int off = 32; off > 0; off >>= 1) mm = fmax(mm, __shfl_down(mm, off));
            if (t == 0) maxn2s = mm;
        }
        __syncthreads();
        double cut2 = maxn2s * (RCOND * RCOND);
        for (int e = t; e < M * M; e += 512) {
            int cc = e >> 7, rr = e & 127;
            double n2 = norms2[cc];
            Wcol[(size_t)blockIdx.x * M * M + e] = (n2 > cut2) ? G[cc * 130 + rr] / n2 : 0.0;
        }
    } else {
        // ======================= B@v (tiled GEMM) =======================
        int bb = blockIdx.x - BH;        // 0..255
        int head = bb >> 2;
        int chunk = bb & 3;
        float* F = (float*)ldsd;
        float* qls = F;                  // [128][68]  8704 f32
        float* kls = F + 8704;           // [64][68]   4352
        float* vls = F + 13056;          // [64][68]   4352
        float* Zl  = F + 17408;          // [64][132]  8448  (f32 E-tile)
        // stage ql once
        {
            const float4* qg = (const float4*)(qlf32 + (size_t)head * M * DHEAD);
            for (int e = t; e < 2048; e += 512) {
                int m = e >> 4, dq = e & 15;
                *(float4*)&qls[m * 68 + dq * 4] = qg[e];
            }
        }
        int mb = t >> 4, lo = t & 15;    // phase1: (mb, kb=lo); phase2: (mb, db=lo)
        double acc64[16];                // [i 4m][4 d]
        double den64[4];
        #pragma unroll
        for (int i = 0; i < 16; ++i) acc64[i] = 0.0;
        #pragma unroll
        for (int i = 0; i < 4; ++i) den64[i] = 0.0;
        size_t keybase = (size_t)head * NSEQ + (size_t)chunk * KPB;
        for (int tt = 0; tt < NTILE; ++tt) {
            __syncthreads();             // previous phase2 done reading kls/vls/Zl
            const float4* kg = (const float4*)(k + (keybase + tt * TILE) * DHEAD);
            const float4* vg = (const float4*)(v + (keybase + tt * TILE) * DHEAD);
            for (int e = t; e < 1024; e += 512) {
                int key = e >> 4, dq = e & 15;
                *(float4*)&kls[key * 68 + dq * 4] = kg[e];
                *(float4*)&vls[key * 68 + dq * 4] = vg[e];
            }
            __syncthreads();
            // phase 1: z[4m][4k] logits + exp -> Zl
            float z0[4], z1[4], z2[4], z3[4];   // z{i}[j]
            #pragma unroll
            for (int j = 0; j < 4; ++j) { z0[j] = 0.f; z1[j] = 0.f; z2[j] = 0.f; z3[j] = 0.f; }
            for (int dc = 0; dc < DHEAD; dc += 4) {
                float4 qr[4], kr[4];
                #pragma unroll
                for (int i = 0; i < 4; ++i) qr[i] = *(const float4*)&qls[(mb * 4 + i) * 68 + dc];
                #pragma unroll
                for (int j = 0; j < 4; ++j) kr[j] = *(const float4*)&kls[(lo * 4 + j) * 68 + dc];
                #pragma unroll
                for (int j = 0; j < 4; ++j) {
                    z0[j] += qr[0].x * kr[j].x + qr[0].y * kr[j].y + qr[0].z * kr[j].z + qr[0].w * kr[j].w;
                    z1[j] += qr[1].x * kr[j].x + qr[1].y * kr[j].y + qr[1].z * kr[j].z + qr[1].w * kr[j].w;
                    z2[j] += qr[2].x * kr[j].x + qr[2].y * kr[j].y + qr[2].z * kr[j].z + qr[2].w * kr[j].w;
                    z3[j] += qr[3].x * kr[j].x + qr[3].y * kr[j].y + qr[3].z * kr[j].z + qr[3].w * kr[j].w;
                }
            }
            #pragma unroll
            for (int j = 0; j < 4; ++j) {
                float4 ej;
                ej.x = __expf(z0[j]); ej.y = __expf(z1[j]);
                ej.z = __expf(z2[j]); ej.w = __expf(z3[j]);
                *(float4*)&Zl[(lo * 4 + j) * 132 + mb * 4] = ej;
            }
            __syncthreads();
            // phase 2: acc[4m][4d] += E[4m][key] * V[key][4d]; f32 tile acc, f64 flush
            float4 a32[4];
            #pragma unroll
            for (int i = 0; i < 4; ++i) a32[i] = make_float4(0.f, 0.f, 0.f, 0.f);
            float den32[4] = {0.f, 0.f, 0.f, 0.f};
            for (int key = 0; key < TILE; ++key) {
                float4 vv = *(const float4*)&vls[key * 68 + lo * 4];
                float4 ee = *(const float4*)&Zl[key * 132 + mb * 4];
                a32[0].x += ee.x * vv.x; a32[0].y += ee.x * vv.y; a32[0].z += ee.x * vv.z; a32[0].w += ee.x * vv.w;
                a32[1].x += ee.y * vv.x; a32[1].y += ee.y * vv.y; a32[1].z += ee.y * vv.z; a32[1].w += ee.y * vv.w;
                a32[2].x += ee.z * vv.x; a32[2].y += ee.z * vv.y; a32[2].z += ee.z * vv.z; a32[2].w += ee.z * vv.w;
                a32[3].x += ee.w * vv.x; a32[3].y += ee.w * vv.y; a32[3].z += ee.w * vv.z; a32[3].w += ee.w * vv.w;
                if (lo == 0) { den32[0] += ee.x; den32[1] += ee.y; den32[2] += ee.z; den32[3] += ee.w; }
            }
            #pragma unroll
            for (int i = 0; i < 4; ++i) {
                acc64[i * 4 + 0] += (double)a32[i].x;
                acc64[i * 4 + 1] += (double)a32[i].y;
                acc64[i * 4 + 2] += (double)a32[i].z;
                acc64[i * 4 + 3] += (double)a32[i].w;
            }
            if (lo == 0) {
                #pragma unroll
                for (int i = 0; i < 4; ++i) den64[i] += (double)den32[i];
            }
        }
        // write partials: numd[head][chunk][m][d] f64, dend[head][chunk][m]
        #pragma unroll
        for (int i = 0; i < 4; ++i) {
            size_t ob = (((size_t)head * NCB + chunk) * M + mb * 4 + i) * DHEAD + lo * 4;
            *(double2*)&numd[ob]     = make_double2(acc64[i * 4 + 0], acc64[i * 4 + 1]);
            *(double2*)&numd[ob + 2] = make_double2(acc64[i * 4 + 2], acc64[i * 4 + 3]);
        }
        if (lo == 0) {
            #pragma unroll
            for (int i = 0; i < 4; ++i)
                dend[((size_t)head * NCB + chunk) * M + mb * 4 + i] = den64[i];
        }
    }
}

// ---------------- Kernel E: fused  Bv reduce -> W^T -> W -> S^T  (f64, ABv out f32) ----
__global__ __launch_bounds__(512) void apply_kernel(const double* __restrict__ numd,
                                                    const double* __restrict__ dend,
                                                    const double* __restrict__ Wcol,
                                                    const double* __restrict__ Sg,
                                                    float* __restrict__ ABvf32) {
    extern __shared__ double lds[];
    double* A_ = lds;                 // [128][66]
    double* B_ = lds + M * 66;
    __shared__ double dsum[M];
    int head = blockIdx.x;
    int t = threadIdx.x;
    if (t < M) {
        double s = 0.0;
        #pragma unroll
        for (int c = 0; c < NCB; ++c) s += dend[((size_t)head * NCB + c) * M + t];
        dsum[t] = s;
    }
    __syncthreads();
    for (int e = t; e < M * DHEAD; e += 512) {
        int mm = e >> 6;
        double s = 0.0;
        #pragma unroll
        for (int c = 0; c < NCB; ++c) s += numd[((size_t)head * NCB + c) * (M * DHEAD) + e];
        A_[mm * 66 + (e & 63)] = s / dsum[mm];
    }
    __syncthreads();
    int i = t >> 3, qd = t & 7;
    const double* Wb = Wcol + (size_t)head * M * M;
    const double* Sb = Sg + (size_t)head * M * M;
    {   // stage 1: B = W^T A
        double a0[8], a1[8];
        #pragma unroll
        for (int d = 0; d < 8; ++d) { a0[d] = 0.0; a1[d] = 0.0; }
        for (int r = 0; r < M; ++r) {
            double m0 = Wb[(size_t)i * M + r];
            double m1 = Wb[(size_t)(i + 64) * M + r];
            #pragma unroll
            for (int d = 0; d < 8; ++d) {
                double xv = A_[r * 66 + qd * 8 + d];
                a0[d] += m0 * xv; a1[d] += m1 * xv;
            }
        }
        #pragma unroll
        for (int d = 0; d < 8; ++d) {
            B_[i * 66 + qd * 8 + d] = a0[d];
            B_[(i + 64) * 66 + qd * 8 + d] = a1[d];
        }
    }
    __syncthreads();
    {   // stage 2: A = W B
        double a0[8], a1[8];
        #pragma unroll
        for (int d = 0; d < 8; ++d) { a0[d] = 0.0; a1[d] = 0.0; }
        for (int r = 0; r < M; ++r) {
            double m0 = Wb[(size_t)r * M + i];
            double m1 = Wb[(size_t)r * M + i + 64];
            #pragma unroll
            for (int d = 0; d < 8; ++d) {
                double xv = B_[r * 66 + qd * 8 + d];
                a0[d] += m0 * xv; a1[d] += m1 * xv;
            }
        }
        #pragma unroll
        for (int d = 0; d < 8; ++d) {
            A_[i * 66 + qd * 8 + d] = a0[d];
            A_[(i + 64) * 66 + qd * 8 + d] = a1[d];
        }
    }
    __syncthreads();
    {   // stage 3: ABv = S^T A
        double a0[8], a1[8];
        #pragma unroll
        for (int d = 0; d < 8; ++d) { a0[d] = 0.0; a1[d] = 0.0; }
        for (int r = 0; r < M; ++r) {
            double m0 = Sb[(size_t)i * M + r];
            double m1 = Sb[(size_t)(i + 64) * M + r];
            #pragma unroll
            for (int d = 0; d < 8; ++d) {
                double xv = A_[r * 66 + qd * 8 + d];
                a0[d] += m0 * xv; a1[d] += m1 * xv;
            }
        }
        float* ob = ABvf32 + (size_t)head * M * DHEAD;
        #pragma unroll
        for (int d = 0; d < 8; ++d) {
            ob[i * DHEAD + qd * 8 + d] = (float)a0[d];
            ob[(i + 64) * DHEAD + qd * 8 + d] = (float)a1[d];
        }
    }
}

// ---------------- Kernel F: out = softmax(q @ kl^T) @ ABv  (f32, 2-row tiling) --------
__global__ __launch_bounds__(512) void out_kernel(const float* __restrict__ q,
                                                  const float* __restrict__ klf32,
                                                  const float* __restrict__ ABvf32,
                                                  float* __restrict__ out) {
    __shared__ float kls[M * DHEAD];
    __shared__ float avs[M * DHEAD];
    int head = blockIdx.x >> 4;
    int tile = blockIdx.x & 15;
    int t = threadIdx.x;
    for (int e = t; e < M * DHEAD; e += 512) {
        kls[e] = klf32[(size_t)head * M * DHEAD + e];
        avs[e] = ABvf32[(size_t)head * M * DHEAD + e];
    }
    __syncthreads();
    int rl = t >> 1, h = t & 1;
    size_t row0 = (size_t)head * NSEQ + (size_t)tile * 512 + rl;
    size_t row1 = row0 + 256;
    const float4* qr0 = (const float4*)(q + row0 * DHEAD + h * 32);
    const float4* qr1 = (const float4*)(q + row1 * DHEAD + h * 32);
    float4 qa[8], qb[8];
    #pragma unroll
    for (int c = 0; c < 8; ++c) {
        float4 x = qr0[c];
        x.x *= 0.125f; x.y *= 0.125f; x.z *= 0.125f; x.w *= 0.125f;
        qa[c] = x;
        float4 y = qr1[c];
        y.x *= 0.125f; y.y *= 0.125f; y.z *= 0.125f; y.w *= 0.125f;
        qb[c] = y;
    }
    float acc0[32], acc1[32];
    #pragma unroll
    for (int d = 0; d < 32; ++d) { acc0[d] = 0.f; acc1[d] = 0.f; }
    float d0 = 0.f, d1 = 0.f;
    for (int mm = 0; mm < M; ++mm) {
        const float4* kr = (const float4*)(kls + mm * DHEAD + h * 32);
        float z0 = 0.f, z1 = 0.f;
        #pragma unroll
        for (int c = 0; c < 8; ++c) {
            float4 kk = kr[c];
            z0 += qa[c].x * kk.x + qa[c].y * kk.y + qa[c].z * kk.z + qa[c].w * kk.w;
            z1 += qb[c].x * kk.x + qb[c].y * kk.y + qb[c].z * kk.z + qb[c].w * kk.w;
        }
        z0 += __shfl_xor(z0, 1);
        z1 += __shfl_xor(z1, 1);
        float e0 = __expf(z0), e1 = __expf(z1);
        d0 += e0; d1 += e1;
        const float4* ar = (const float4*)(avs + mm * DHEAD + h * 32);
        #pragma unroll
        for (int c = 0; c < 8; ++c) {
            float4 av = ar[c];
            acc0[4 * c]     += e0 * av.x; acc0[4 * c + 1] += e0 * av.y;
            acc0[4 * c + 2] += e0 * av.z; acc0[4 * c + 3] += e0 * av.w;
            acc1[4 * c]     += e1 * av.x; acc1[4 * c + 1] += e1 * av.y;
            acc1[4 * c + 2] += e1 * av.z; acc1[4 * c + 3] += e1 * av.w;
        }
    }
    float i0 = 1.f / d0, i1 = 1.f / d1;
    float* o0 = out + row0 * DHEAD + h * 32;
    float* o1 = out + row1 * DHEAD + h * 32;
    #pragma unroll
    for (int d = 0; d < 32; ++d) { o0[d] = acc0[d] * i0; o1[d] = acc1[d] * i1; }
}

extern "C" void kernel_launch(void* const* d_in, const int* in_sizes, int n_in,
                              void* d_out, int out_size, void* d_ws, size_t ws_size,
                              hipStream_t stream) {
    const float* q = (const float*)d_in[0];
    const float* k = (const float*)d_in[1];
    const float* v = (const float*)d_in[2];
    float* out = (float*)d_out;
    char* ws = (char*)d_ws;
    // ws map. ql64/kl64 [0,8M) die after s_kernel; numd [0,16M) written by fused.
    double* ql64  = (double*)(ws + 0);            //  4 MB
    double* kl64  = (double*)(ws + 4194304);      //  4 MB
    double* numd  = (double*)(ws + 0);            // 16 MB (after s_kernel)
    double* dend  = (double*)(ws + 33554432);     //  256 KB
    float*  qlf32 = (float*)(ws + 34078720);      //  2 MB
    float*  klf32 = (float*)(ws + 36175872);      //  2 MB
    double* Sg    = (double*)(ws + 38273024);     //  8 MB (S col-major)
    double* Wcol  = (double*)(ws + 46661632);     //  8 MB
    float*  ABvf32= (float*)(ws + 55050240);      //  2 MB

    lm_kernel<<<16384, 64, 0, stream>>>(q, k, ql64, kl64, qlf32, klf32);
    s_kernel<<<BH, 512, 2 * M * DHEAD * 8, stream>>>(ql64, kl64, Sg);
    fused_kernel<<<BH + 256, 512, 133120, stream>>>(Sg, Wcol, k, v, qlf32, numd, dend);
    apply_kernel<<<BH, 512, 2 * M * 66 * 8, stream>>>(numd, dend, Wcol, Sg, ABvf32);
    out_kernel<<<BH * 16, 512, 0, stream>>>(q, klf32, ABvf32, out);
}

// Round 8
// 2598.045 us; speedup vs baseline: 2.1646x; 1.2456x over previous
//
#include <hip/hip_runtime.h>
#include <hip/hip_bf16.h>
#include <math.h>

#define BH 64
#define NSEQ 8192
#define DHEAD 64
#define M 128
#define LGRP 64
#define NCB 4
#define KPB (NSEQ / NCB)    // 2048 keys per bv block
#define TILE 64             // keys per LDS tile
#define NTILE (KPB / TILE)  // 32
#define NSWEEP 8
#define NROUND 127
#define RCOND 1.52587890625e-4   // 10 * 128 * eps_f32 (jax f32 pinv rtol)

// ---------------- Kernel A: landmarks (f64 pooling, q scaled by 1/8) ----------------
__global__ __launch_bounds__(64) void lm_kernel(const float* __restrict__ q,
                                                const float* __restrict__ k,
                                                double* __restrict__ ql64,
                                                double* __restrict__ kl64,
                                                float* __restrict__ qlf32,
                                                float* __restrict__ klf32) {
    int idx = blockIdx.x;            // 0..16383
    int tensor = idx >> 13;          // 0 = q, 1 = k
    int g = idx & 8191;
    int head = g >> 7, m = g & 127;
    int d = threadIdx.x;
    const float* src = tensor ? k : q;
    const float* base = src + ((size_t)head * NSEQ + (size_t)m * LGRP) * DHEAD + d;
    double s = 0.0;
    #pragma unroll 8
    for (int r = 0; r < LGRP; ++r) s += (double)base[(size_t)r * DHEAD];
    s *= (1.0 / LGRP);
    if (!tensor) s *= 0.125;         // q / sqrt(64)
    size_t o = (size_t)head * M * DHEAD + (size_t)m * DHEAD + d;
    if (!tensor) { ql64[o] = s; qlf32[o] = (float)s; }
    else         { kl64[o] = s; klf32[o] = (float)s; }
}

// ---------------- Kernel B: S = softmax(ql @ kl^T) f64, stored COLUMN-major ----------------
__global__ __launch_bounds__(512) void s_kernel(const double* __restrict__ ql64,
                                                const double* __restrict__ kl64,
                                                double* __restrict__ Sg) {
    extern __shared__ double lds[];      // qlds[8192] | klds[8192]
    double* qlds = lds;
    double* klds = lds + M * DHEAD;
    int head = blockIdx.x;
    int t = threadIdx.x;
    const double2* qg = (const double2*)(ql64 + (size_t)head * M * DHEAD);
    const double2* kg = (const double2*)(kl64 + (size_t)head * M * DHEAD);
    for (int e = t; e < M * DHEAD / 2; e += 512) {
        ((double2*)qlds)[e] = qg[e];
        ((double2*)klds)[e] = kg[e];
    }
    __syncthreads();
    int tr = t >> 4, tc = t & 15;
    double acc[4][8];
    #pragma unroll
    for (int i = 0; i < 4; ++i)
        #pragma unroll
        for (int j = 0; j < 8; ++j) acc[i][j] = 0.0;
    for (int dc = 0; dc < DHEAD; dc += 4) {
        double qreg[4][4], kreg[8][4];
        #pragma unroll
        for (int i = 0; i < 4; ++i)
            #pragma unroll
            for (int d = 0; d < 4; ++d) qreg[i][d] = qlds[(4 * tr + i) * DHEAD + dc + d];
        #pragma unroll
        for (int j = 0; j < 8; ++j)
            #pragma unroll
            for (int d = 0; d < 4; ++d) kreg[j][d] = klds[(8 * tc + j) * DHEAD + dc + d];
        #pragma unroll
        for (int i = 0; i < 4; ++i)
            #pragma unroll
            for (int j = 0; j < 8; ++j)
                #pragma unroll
                for (int d = 0; d < 4; ++d) acc[i][j] += qreg[i][d] * kreg[j][d];
    }
    double* So = Sg + (size_t)head * M * M;
    #pragma unroll
    for (int i = 0; i < 4; ++i) {
        double mx = acc[i][0];
        #pragma unroll
        for (int j = 1; j < 8; ++j) mx = fmax(mx, acc[i][j]);
        mx = fmax(mx, __shfl_xor(mx, 1));
        mx = fmax(mx, __shfl_xor(mx, 2));
        mx = fmax(mx, __shfl_xor(mx, 4));
        mx = fmax(mx, __shfl_xor(mx, 8));
        double sum = 0.0;
        #pragma unroll
        for (int j = 0; j < 8; ++j) { acc[i][j] = exp(acc[i][j] - mx); sum += acc[i][j]; }
        sum += __shfl_xor(sum, 1); sum += __shfl_xor(sum, 2);
        sum += __shfl_xor(sum, 4); sum += __shfl_xor(sum, 8);
        double inv = 1.0 / sum;
        #pragma unroll
        for (int j = 0; j < 8; ++j)
            So[(size_t)(8 * tc + j) * M + 4 * tr + i] = acc[i][j] * inv;   // col-major
    }
}

// ---------------- Fused: Jacobi SVD + Wcol (blocks 0..63)  ||  B@v GEMM (blocks 64..319) ----
// Jacobi: LDS-resident [col][130] f64, cached norms (c-dot only), safe junk-pair skip
// (na+nb<kc: rotation preserves na+nb so pair can never become kept), kept-kept-only
// convergence exit (output error ~ kept-kept non-orthogonality; kept-junk is damped by
// sigma_junk/sigma_kept in the S^T U Sigma^-2 U^T sandwich).
__global__ __launch_bounds__(512) void fused_kernel(const double* __restrict__ Sg,
                                                    double* __restrict__ Wcol,
                                                    const float* __restrict__ k,
                                                    const float* __restrict__ v,
                                                    const float* __restrict__ qlf32,
                                                    double* __restrict__ numd,
                                                    double* __restrict__ dend) {
    extern __shared__ double ldsd[];     // 133,120 B shared by both paths
    __shared__ double norms2[M];
    __shared__ double maxn2s;
    __shared__ int anyrot, done;
    int t = threadIdx.x;

    if (blockIdx.x < BH) {
        // ======================= Jacobi =======================
        int head = blockIdx.x;
        double* G = ldsd;                // [128][130]
        const double2* Sh2 = (const double2*)(Sg + (size_t)head * M * M);
        double2* G2 = (double2*)G;
        for (int e = t; e < M * 64; e += 512) {
            int col = e >> 6, rp = e & 63;
            G2[col * 65 + rp] = Sh2[e];
        }
        __syncthreads();
        {   // initial norms^2
            int col = t >> 2, qd = t & 3;
            double s = 0.0;
            #pragma unroll 8
            for (int x = qd * 32; x < qd * 32 + 32; ++x) { double vv = G[col * 130 + x]; s += vv * vv; }
            s += __shfl_xor(s, 1); s += __shfl_xor(s, 2);
            if (qd == 0) norms2[col] = s;
        }
        if (t == 0) { anyrot = 1; done = 0; }
        __syncthreads();
        int grp = t >> 3, s8 = t & 7;
        for (int sweep = 0; sweep < NSWEEP; ++sweep) {
            if (t < 64) {
                double mm = fmax(norms2[t], norms2[t + 64]);
                for (int off = 32; off > 0; off >>= 1) mm = fmax(mm, __shfl_down(mm, off));
                if (t == 0) {
                    maxn2s = mm;
                    done = (sweep > 0 && anyrot == 0);
                    anyrot = 0;
                }
            }
            __syncthreads();
            if (done) break;
            double kc = maxn2s * (RCOND * RCOND);   // kept-column threshold on norm^2
            for (int r = 0; r < NROUND; ++r) {
                int ca, cb;
                if (grp == 0) { ca = 127; cb = r; }
                else { ca = (r + grp) % 127; cb = (r + 127 - grp) % 127; }
                double na = norms2[ca], nb = norms2[cb];
                if (na + nb >= kc) {       // safe skip: pair can never produce a kept column
                    double2* gA = (double2*)(G + ca * 130);
                    double2* gB = (double2*)(G + cb * 130);
                    double2 va[8], vb[8];
                    #pragma unroll
                    for (int j = 0; j < 8; ++j) va[j] = gA[j * 8 + s8];
                    #pragma unroll
                    for (int j = 0; j < 8; ++j) vb[j] = gB[j * 8 + s8];
                    double c = 0.0;
                    #pragma unroll
                    for (int j = 0; j < 8; ++j) c += va[j].x * vb[j].x + va[j].y * vb[j].y;
                    c += __shfl_xor(c, 1); c += __shfl_xor(c, 2); c += __shfl_xor(c, 4);
                    if (c * c > 1e-24 * na * nb) {
                        if (na > kc && nb > kc && c * c > 1e-12 * na * nb) anyrot = 1;
                        double zeta = (nb - na) / (2.0 * c);
                        double tt = (zeta >= 0.0 ? 1.0 : -1.0) / (fabs(zeta) + sqrt(1.0 + zeta * zeta));
                        double cs = 1.0 / sqrt(1.0 + tt * tt);
                        double sn = cs * tt;
                        #pragma unroll
                        for (int j = 0; j < 8; ++j) {
                            double nax = cs * va[j].x - sn * vb[j].x;
                            double nay = cs * va[j].y - sn * vb[j].y;
                            double nbx = sn * va[j].x + cs * vb[j].x;
                            double nby = sn * va[j].y + cs * vb[j].y;
                            gA[j * 8 + s8] = make_double2(nax, nay);
                            gB[j * 8 + s8] = make_double2(nbx, nby);
                        }
                        if (s8 == 0) {
                            norms2[ca] = fmax(na - tt * c, 0.0);
                            norms2[cb] = nb + tt * c;
                        }
                    }
                }
                __syncthreads();
            }
        }
        // exact norms + truncation + W = u / sigma^2
        {
            int col = t >> 2, qd = t & 3;
            double s = 0.0;
            #pragma unroll 8
            for (int x = qd * 32; x < qd * 32 + 32; ++x) { double vv = G[col * 130 + x]; s += vv * vv; }
            s += __shfl_xor(s, 1); s += __shfl_xor(s, 2);
            if (qd == 0) norms2[col] = s;
        }
        __syncthreads();
        if (t < 64) {
            double mm = fmax(norms2[t], norms2[t + 64]);
            for (int off = 32; off > 0; off >>= 1) mm = fmax(mm, __shfl_down(mm, off));
            if (t == 0) maxn2s = mm;
        }
        __syncthreads();
        double cut2 = maxn2s * (RCOND * RCOND);
        for (int e = t; e < M * M; e += 512) {
            int cc = e >> 7, rr = e & 127;
            double n2 = norms2[cc];
            Wcol[(size_t)blockIdx.x * M * M + e] = (n2 > cut2) ? G[cc * 130 + rr] / n2 : 0.0;
        }
    } else {
        // ======================= B@v (tiled GEMM) =======================
        int bb = blockIdx.x - BH;        // 0..255
        int head = bb >> 2;
        int chunk = bb & 3;
        float* F = (float*)ldsd;
        float* qls = F;                  // [128][68]  8704 f32
        float* kls = F + 8704;           // [64][68]   4352
        float* vls = F + 13056;          // [64][68]   4352
        float* Zl  = F + 17408;          // [64][132]  8448  (f32 E-tile, [key][m])
        // stage ql once
        {
            const float4* qg = (const float4*)(qlf32 + (size_t)head * M * DHEAD);
            for (int e = t; e < 2048; e += 512) {
                int m = e >> 4, dq = e & 15;
                *(float4*)&qls[m * 68 + dq * 4] = qg[e];
            }
        }
        int mb = t >> 4, lo = t & 15;    // phase1: keys j*16+lo; phase2: (mb, db=lo)
        double acc64[16];                // [i 4m][4 d]
        double den64[4];
        #pragma unroll
        for (int i = 0; i < 16; ++i) acc64[i] = 0.0;
        #pragma unroll
        for (int i = 0; i < 4; ++i) den64[i] = 0.0;
        size_t keybase = (size_t)head * NSEQ + (size_t)chunk * KPB;
        for (int tt = 0; tt < NTILE; ++tt) {
            __syncthreads();             // previous phase2 done reading kls/vls/Zl
            const float4* kg = (const float4*)(k + (keybase + tt * TILE) * DHEAD);
            const float4* vg = (const float4*)(v + (keybase + tt * TILE) * DHEAD);
            for (int e = t; e < 1024; e += 512) {
                int key = e >> 4, dq = e & 15;
                *(float4*)&kls[key * 68 + dq * 4] = kg[e];
                *(float4*)&vls[key * 68 + dq * 4] = vg[e];
            }
            __syncthreads();
            // phase 1: z[4m][4k] logits + exp -> Zl ; keys = j*16+lo (bank-friendly stride)
            float z0[4], z1[4], z2[4], z3[4];   // z{i}[j]
            #pragma unroll
            for (int j = 0; j < 4; ++j) { z0[j] = 0.f; z1[j] = 0.f; z2[j] = 0.f; z3[j] = 0.f; }
            for (int dc = 0; dc < DHEAD; dc += 4) {
                float4 qr[4], kr[4];
                #pragma unroll
                for (int i = 0; i < 4; ++i) qr[i] = *(const float4*)&qls[(mb * 4 + i) * 68 + dc];
                #pragma unroll
                for (int j = 0; j < 4; ++j) kr[j] = *(const float4*)&kls[(j * 16 + lo) * 68 + dc];
                #pragma unroll
                for (int j = 0; j < 4; ++j) {
                    z0[j] += qr[0].x * kr[j].x + qr[0].y * kr[j].y + qr[0].z * kr[j].z + qr[0].w * kr[j].w;
                    z1[j] += qr[1].x * kr[j].x + qr[1].y * kr[j].y + qr[1].z * kr[j].z + qr[1].w * kr[j].w;
                    z2[j] += qr[2].x * kr[j].x + qr[2].y * kr[j].y + qr[2].z * kr[j].z + qr[2].w * kr[j].w;
                    z3[j] += qr[3].x * kr[j].x + qr[3].y * kr[j].y + qr[3].z * kr[j].z + qr[3].w * kr[j].w;
                }
            }
            #pragma unroll
            for (int j = 0; j < 4; ++j) {
                float4 ej;
                ej.x = __expf(z0[j]); ej.y = __expf(z1[j]);
                ej.z = __expf(z2[j]); ej.w = __expf(z3[j]);
                *(float4*)&Zl[(j * 16 + lo) * 132 + mb * 4] = ej;
            }
            __syncthreads();
            // phase 2: acc[4m][4d] += E[4m][key] * V[key][4d]; f32 tile acc, f64 flush
            float4 a32[4];
            #pragma unroll
            for (int i = 0; i < 4; ++i) a32[i] = make_float4(0.f, 0.f, 0.f, 0.f);
            float den32[4] = {0.f, 0.f, 0.f, 0.f};
            for (int key = 0; key < TILE; ++key) {
                float4 vv = *(const float4*)&vls[key * 68 + lo * 4];
                float4 ee = *(const float4*)&Zl[key * 132 + mb * 4];
                a32[0].x += ee.x * vv.x; a32[0].y += ee.x * vv.y; a32[0].z += ee.x * vv.z; a32[0].w += ee.x * vv.w;
                a32[1].x += ee.y * vv.x; a32[1].y += ee.y * vv.y; a32[1].z += ee.y * vv.z; a32[1].w += ee.y * vv.w;
                a32[2].x += ee.z * vv.x; a32[2].y += ee.z * vv.y; a32[2].z += ee.z * vv.z; a32[2].w += ee.z * vv.w;
                a32[3].x += ee.w * vv.x; a32[3].y += ee.w * vv.y; a32[3].z += ee.w * vv.z; a32[3].w += ee.w * vv.w;
                if (lo == 0) { den32[0] += ee.x; den32[1] += ee.y; den32[2] += ee.z; den32[3] += ee.w; }
            }
            #pragma unroll
            for (int i = 0; i < 4; ++i) {
                acc64[i * 4 + 0] += (double)a32[i].x;
                acc64[i * 4 + 1] += (double)a32[i].y;
                acc64[i * 4 + 2] += (double)a32[i].z;
                acc64[i * 4 + 3] += (double)a32[i].w;
            }
            if (lo == 0) {
                #pragma unroll
                for (int i = 0; i < 4; ++i) den64[i] += (double)den32[i];
            }
        }
        // write partials: numd[head][chunk][m][d] f64, dend[head][chunk][m]
        #pragma unroll
        for (int i = 0; i < 4; ++i) {
            size_t ob = (((size_t)head * NCB + chunk) * M + mb * 4 + i) * DHEAD + lo * 4;
            *(double2*)&numd[ob]     = make_double2(acc64[i * 4 + 0], acc64[i * 4 + 1]);
            *(double2*)&numd[ob + 2] = make_double2(acc64[i * 4 + 2], acc64[i * 4 + 3]);
        }
        if (lo == 0) {
            #pragma unroll
            for (int i = 0; i < 4; ++i)
                dend[((size_t)head * NCB + chunk) * M + mb * 4 + i] = den64[i];
        }
    }
}

// ---------------- Kernel E: fused  Bv reduce -> W^T -> W -> S^T  (f64, ABv out f32) ----
__global__ __launch_bounds__(512) void apply_kernel(const double* __restrict__ numd,
                                                    const double* __restrict__ dend,
                                                    const double* __restrict__ Wcol,
                                                    const double* __restrict__ Sg,
                                                    float* __restrict__ ABvf32) {
    extern __shared__ double lds[];
    double* A_ = lds;                 // [128][66]
    double* B_ = lds + M * 66;
    __shared__ double dsum[M];
    int head = blockIdx.x;
    int t = threadIdx.x;
    if (t < M) {
        double s = 0.0;
        #pragma unroll
        for (int c = 0; c < NCB; ++c) s += dend[((size_t)head * NCB + c) * M + t];
        dsum[t] = s;
    }
    __syncthreads();
    for (int e = t; e < M * DHEAD; e += 512) {
        int mm = e >> 6;
        double s = 0.0;
        #pragma unroll
        for (int c = 0; c < NCB; ++c) s += numd[((size_t)head * NCB + c) * (M * DHEAD) + e];
        A_[mm * 66 + (e & 63)] = s / dsum[mm];
    }
    __syncthreads();
    int i = t >> 3, qd = t & 7;
    const double* Wb = Wcol + (size_t)head * M * M;
    const double* Sb = Sg + (size_t)head * M * M;
    {   // stage 1: B = W^T A
        double a0[8], a1[8];
        #pragma unroll
        for (int d = 0; d < 8; ++d) { a0[d] = 0.0; a1[d] = 0.0; }
        for (int r = 0; r < M; ++r) {
            double m0 = Wb[(size_t)i * M + r];
            double m1 = Wb[(size_t)(i + 64) * M + r];
            #pragma unroll
            for (int d = 0; d < 8; ++d) {
                double xv = A_[r * 66 + qd * 8 + d];
                a0[d] += m0 * xv; a1[d] += m1 * xv;
            }
        }
        #pragma unroll
        for (int d = 0; d < 8; ++d) {
            B_[i * 66 + qd * 8 + d] = a0[d];
            B_[(i + 64) * 66 + qd * 8 + d] = a1[d];
        }
    }
    __syncthreads();
    {   // stage 2: A = W B
        double a0[8], a1[8];
        #pragma unroll
        for (int d = 0; d < 8; ++d) { a0[d] = 0.0; a1[d] = 0.0; }
        for (int r = 0; r < M; ++r) {
            double m0 = Wb[(size_t)r * M + i];
            double m1 = Wb[(size_t)r * M + i + 64];
            #pragma unroll
            for (int d = 0; d < 8; ++d) {
                double xv = B_[r * 66 + qd * 8 + d];
                a0[d] += m0 * xv; a1[d] += m1 * xv;
            }
        }
        #pragma unroll
        for (int d = 0; d < 8; ++d) {
            A_[i * 66 + qd * 8 + d] = a0[d];
            A_[(i + 64) * 66 + qd * 8 + d] = a1[d];
        }
    }
    __syncthreads();
    {   // stage 3: ABv = S^T A
        double a0[8], a1[8];
        #pragma unroll
        for (int d = 0; d < 8; ++d) { a0[d] = 0.0; a1[d] = 0.0; }
        for (int r = 0; r < M; ++r) {
            double m0 = Sb[(size_t)i * M + r];
            double m1 = Sb[(size_t)(i + 64) * M + r];
            #pragma unroll
            for (int d = 0; d < 8; ++d) {
                double xv = A_[r * 66 + qd * 8 + d];
                a0[d] += m0 * xv; a1[d] += m1 * xv;
            }
        }
        float* ob = ABvf32 + (size_t)head * M * DHEAD;
        #pragma unroll
        for (int d = 0; d < 8; ++d) {
            ob[i * DHEAD + qd * 8 + d] = (float)a0[d];
            ob[(i + 64) * DHEAD + qd * 8 + d] = (float)a1[d];
        }
    }
}

// ---------------- Kernel F: out = softmax(q @ kl^T) @ ABv  (f32, 2-row tiling) --------
__global__ __launch_bounds__(512) void out_kernel(const float* __restrict__ q,
                                                  const float* __restrict__ klf32,
                                                  const float* __restrict__ ABvf32,
                                                  float* __restrict__ out) {
    __shared__ float kls[M * DHEAD];
    __shared__ float avs[M * DHEAD];
    int head = blockIdx.x >> 4;
    int tile = blockIdx.x & 15;
    int t = threadIdx.x;
    for (int e = t; e < M * DHEAD; e += 512) {
        kls[e] = klf32[(size_t)head * M * DHEAD + e];
        avs[e] = ABvf32[(size_t)head * M * DHEAD + e];
    }
    __syncthreads();
    int rl = t >> 1, h = t & 1;
    size_t row0 = (size_t)head * NSEQ + (size_t)tile * 512 + rl;
    size_t row1 = row0 + 256;
    const float4* qr0 = (const float4*)(q + row0 * DHEAD + h * 32);
    const float4* qr1 = (const float4*)(q + row1 * DHEAD + h * 32);
    float4 qa[8], qb[8];
    #pragma unroll
    for (int c = 0; c < 8; ++c) {
        float4 x = qr0[c];
        x.x *= 0.125f; x.y *= 0.125f; x.z *= 0.125f; x.w *= 0.125f;
        qa[c] = x;
        float4 y = qr1[c];
        y.x *= 0.125f; y.y *= 0.125f; y.z *= 0.125f; y.w *= 0.125f;
        qb[c] = y;
    }
    float acc0[32], acc1[32];
    #pragma unroll
    for (int d = 0; d < 32; ++d) { acc0[d] = 0.f; acc1[d] = 0.f; }
    float d0 = 0.f, d1 = 0.f;
    for (int mm = 0; mm < M; ++mm) {
        const float4* kr = (const float4*)(kls + mm * DHEAD + h * 32);
        float z0 = 0.f, z1 = 0.f;
        #pragma unroll
        for (int c = 0; c < 8; ++c) {
            float4 kk = kr[c];
            z0 += qa[c].x * kk.x + qa[c].y * kk.y + qa[c].z * kk.z + qa[c].w * kk.w;
            z1 += qb[c].x * kk.x + qb[c].y * kk.y + qb[c].z * kk.z + qb[c].w * kk.w;
        }
        z0 += __shfl_xor(z0, 1);
        z1 += __shfl_xor(z1, 1);
        float e0 = __expf(z0), e1 = __expf(z1);
        d0 += e0; d1 += e1;
        const float4* ar = (const float4*)(avs + mm * DHEAD + h * 32);
        #pragma unroll
        for (int c = 0; c < 8; ++c) {
            float4 av = ar[c];
            acc0[4 * c]     += e0 * av.x; acc0[4 * c + 1] += e0 * av.y;
            acc0[4 * c + 2] += e0 * av.z; acc0[4 * c + 3] += e0 * av.w;
            acc1[4 * c]     += e1 * av.x; acc1[4 * c + 1] += e1 * av.y;
            acc1[4 * c + 2] += e1 * av.z; acc1[4 * c + 3] += e1 * av.w;
        }
    }
    float i0 = 1.f / d0, i1 = 1.f / d1;
    float* o0 = out + row0 * DHEAD + h * 32;
    float* o1 = out + row1 * DHEAD + h * 32;
    #pragma unroll
    for (int d = 0; d < 32; ++d) { o0[d] = acc0[d] * i0; o1[d] = acc1[d] * i1; }
}

extern "C" void kernel_launch(void* const* d_in, const int* in_sizes, int n_in,
                              void* d_out, int out_size, void* d_ws, size_t ws_size,
                              hipStream_t stream) {
    const float* q = (const float*)d_in[0];
    const float* k = (const float*)d_in[1];
    const float* v = (const float*)d_in[2];
    float* out = (float*)d_out;
    char* ws = (char*)d_ws;
    // ws map. ql64/kl64 [0,8M) die after s_kernel; numd [0,16M) written by fused.
    double* ql64  = (double*)(ws + 0);            //  4 MB
    double* kl64  = (double*)(ws + 4194304);      //  4 MB
    double* numd  = (double*)(ws + 0);            // 16 MB (after s_kernel)
    double* dend  = (double*)(ws + 33554432);     //  256 KB
    float*  qlf32 = (float*)(ws + 34078720);      //  2 MB
    float*  klf32 = (float*)(ws + 36175872);      //  2 MB
    double* Sg    = (double*)(ws + 38273024);     //  8 MB (S col-major)
    double* Wcol  = (double*)(ws + 46661632);     //  8 MB
    float*  ABvf32= (float*)(ws + 55050240);      //  2 MB

    lm_kernel<<<16384, 64, 0, stream>>>(q, k, ql64, kl64, qlf32, klf32);
    s_kernel<<<BH, 512, 2 * M * DHEAD * 8, stream>>>(ql64, kl64, Sg);
    fused_kernel<<<BH + 256, 512, 133120, stream>>>(Sg, Wcol, k, v, qlf32, numd, dend);
    apply_kernel<<<BH, 512, 2 * M * 66 * 8, stream>>>(numd, dend, Wcol, Sg, ABvf32);
    out_kernel<<<BH * 16, 512, 0, stream>>>(q, klf32, ABvf32, out);
}

// Round 9
// 2245.174 us; speedup vs baseline: 2.5049x; 1.1572x over previous
//
#include <hip/hip_runtime.h>
#include <hip/hip_bf16.h>
#include <math.h>

#define BH 64
#define NSEQ 8192
#define DHEAD 64
#define M 128
#define LGRP 64
#define NCB 4
#define KPB (NSEQ / NCB)    // 2048 keys per bv block
#define TILE 64             // keys per LDS tile
#define NTILE (KPB / TILE)  // 32
#define NSWEEP64 3
#define NSWEEP 8
#define NROUND 127
#define RCOND 1.52587890625e-4   // 10 * 128 * eps_f32 (jax f32 pinv rtol)

// ---------------- Kernel A: landmarks (f64 pooling, q scaled by 1/8) ----------------
__global__ __launch_bounds__(64) void lm_kernel(const float* __restrict__ q,
                                                const float* __restrict__ k,
                                                double* __restrict__ ql64,
                                                double* __restrict__ kl64,
                                                float* __restrict__ qlf32,
                                                float* __restrict__ klf32) {
    int idx = blockIdx.x;            // 0..16383
    int tensor = idx >> 13;          // 0 = q, 1 = k
    int g = idx & 8191;
    int head = g >> 7, m = g & 127;
    int d = threadIdx.x;
    const float* src = tensor ? k : q;
    const float* base = src + ((size_t)head * NSEQ + (size_t)m * LGRP) * DHEAD + d;
    double s = 0.0;
    #pragma unroll 8
    for (int r = 0; r < LGRP; ++r) s += (double)base[(size_t)r * DHEAD];
    s *= (1.0 / LGRP);
    if (!tensor) s *= 0.125;         // q / sqrt(64)
    size_t o = (size_t)head * M * DHEAD + (size_t)m * DHEAD + d;
    if (!tensor) { ql64[o] = s; qlf32[o] = (float)s; }
    else         { kl64[o] = s; klf32[o] = (float)s; }
}

// ---------------- Kernel B: S = softmax(ql @ kl^T) f64, stored COLUMN-major ----------------
__global__ __launch_bounds__(512) void s_kernel(const double* __restrict__ ql64,
                                                const double* __restrict__ kl64,
                                                double* __restrict__ Sg) {
    extern __shared__ double lds[];      // qlds[8192] | klds[8192]
    double* qlds = lds;
    double* klds = lds + M * DHEAD;
    int head = blockIdx.x;
    int t = threadIdx.x;
    const double2* qg = (const double2*)(ql64 + (size_t)head * M * DHEAD);
    const double2* kg = (const double2*)(kl64 + (size_t)head * M * DHEAD);
    for (int e = t; e < M * DHEAD / 2; e += 512) {
        ((double2*)qlds)[e] = qg[e];
        ((double2*)klds)[e] = kg[e];
    }
    __syncthreads();
    int tr = t >> 4, tc = t & 15;
    double acc[4][8];
    #pragma unroll
    for (int i = 0; i < 4; ++i)
        #pragma unroll
        for (int j = 0; j < 8; ++j) acc[i][j] = 0.0;
    for (int dc = 0; dc < DHEAD; dc += 4) {
        double qreg[4][4], kreg[8][4];
        #pragma unroll
        for (int i = 0; i < 4; ++i)
            #pragma unroll
            for (int d = 0; d < 4; ++d) qreg[i][d] = qlds[(4 * tr + i) * DHEAD + dc + d];
        #pragma unroll
        for (int j = 0; j < 8; ++j)
            #pragma unroll
            for (int d = 0; d < 4; ++d) kreg[j][d] = klds[(8 * tc + j) * DHEAD + dc + d];
        #pragma unroll
        for (int i = 0; i < 4; ++i)
            #pragma unroll
            for (int j = 0; j < 8; ++j)
                #pragma unroll
                for (int d = 0; d < 4; ++d) acc[i][j] += qreg[i][d] * kreg[j][d];
    }
    double* So = Sg + (size_t)head * M * M;
    #pragma unroll
    for (int i = 0; i < 4; ++i) {
        double mx = acc[i][0];
        #pragma unroll
        for (int j = 1; j < 8; ++j) mx = fmax(mx, acc[i][j]);
        mx = fmax(mx, __shfl_xor(mx, 1));
        mx = fmax(mx, __shfl_xor(mx, 2));
        mx = fmax(mx, __shfl_xor(mx, 4));
        mx = fmax(mx, __shfl_xor(mx, 8));
        double sum = 0.0;
        #pragma unroll
        for (int j = 0; j < 8; ++j) { acc[i][j] = exp(acc[i][j] - mx); sum += acc[i][j]; }
        sum += __shfl_xor(sum, 1); sum += __shfl_xor(sum, 2);
        sum += __shfl_xor(sum, 4); sum += __shfl_xor(sum, 8);
        double inv = 1.0 / sum;
        #pragma unroll
        for (int j = 0; j < 8; ++j)
            So[(size_t)(8 * tc + j) * M + 4 * tr + i] = acc[i][j] * inv;   // col-major
    }
}

// ---------------- Fused: hybrid Jacobi SVD (blocks 0..63) || B@v GEMM (blocks 64..319) ----
// Jacobi: sweeps 0..2 in f64 [col][130] (cancellation phase: junk columns FORM here),
// then in-place convert to f32 [col][132] for sweeps 3..7 (2x LDS traffic + FMA rate).
// Norm bookkeeping stays f64 (analytic updates; exact recompute at end). Safe junk-pair
// skip (na+nb<kc), kept-kept-only convergence exit (|corr|>4e-6).
__global__ __launch_bounds__(512) void fused_kernel(const double* __restrict__ Sg,
                                                    double* __restrict__ Wcol,
                                                    const float* __restrict__ k,
                                                    const float* __restrict__ v,
                                                    const float* __restrict__ qlf32,
                                                    double* __restrict__ numd,
                                                    double* __restrict__ dend) {
    extern __shared__ double ldsd[];     // 133,120 B shared by both paths
    __shared__ double norms2[M];
    __shared__ double maxn2s;
    __shared__ int anyrot, done;
    int t = threadIdx.x;

    if (blockIdx.x < BH) {
        // ======================= Jacobi =======================
        int head = blockIdx.x;
        double* G = ldsd;                // f64 [128][130]
        float* G32 = (float*)ldsd;       // f32 [128][132] (after conversion)
        const double2* Sh2 = (const double2*)(Sg + (size_t)head * M * M);
        double2* G2 = (double2*)G;
        for (int e = t; e < M * 64; e += 512) {
            int col = e >> 6, rp = e & 63;
            G2[col * 65 + rp] = Sh2[e];
        }
        __syncthreads();
        {   // initial norms^2
            int col = t >> 2, qd = t & 3;
            double s = 0.0;
            #pragma unroll 8
            for (int x = qd * 32; x < qd * 32 + 32; ++x) { double vv = G[col * 130 + x]; s += vv * vv; }
            s += __shfl_xor(s, 1); s += __shfl_xor(s, 2);
            if (qd == 0) norms2[col] = s;
        }
        if (t == 0) { anyrot = 1; done = 0; }
        __syncthreads();
        int grp = t >> 3, s8 = t & 7;
        int sweep = 0;
        // ---------- phase 1: f64 sweeps ----------
        for (; sweep < NSWEEP64; ++sweep) {
            if (t < 64) {
                double mm = fmax(norms2[t], norms2[t + 64]);
                for (int off = 32; off > 0; off >>= 1) mm = fmax(mm, __shfl_down(mm, off));
                if (t == 0) {
                    maxn2s = mm;
                    done = (sweep > 0 && anyrot == 0);
                    anyrot = 0;
                }
            }
            __syncthreads();
            if (done) break;
            double kc = maxn2s * (RCOND * RCOND);
            for (int r = 0; r < NROUND; ++r) {
                int ca, cb;
                if (grp == 0) { ca = 127; cb = r; }
                else { ca = (r + grp) % 127; cb = (r + 127 - grp) % 127; }
                double na = norms2[ca], nb = norms2[cb];
                if (na + nb >= kc) {       // safe skip: pair can never yield a kept column
                    double2* gA = (double2*)(G + ca * 130);
                    double2* gB = (double2*)(G + cb * 130);
                    double2 va[8], vb[8];
                    #pragma unroll
                    for (int j = 0; j < 8; ++j) va[j] = gA[j * 8 + s8];
                    #pragma unroll
                    for (int j = 0; j < 8; ++j) vb[j] = gB[j * 8 + s8];
                    double c = 0.0;
                    #pragma unroll
                    for (int j = 0; j < 8; ++j) c += va[j].x * vb[j].x + va[j].y * vb[j].y;
                    c += __shfl_xor(c, 1); c += __shfl_xor(c, 2); c += __shfl_xor(c, 4);
                    if (c * c > 1e-24 * na * nb) {
                        if (na > kc && nb > kc && c * c > 1.6e-11 * na * nb) anyrot = 1;
                        double zeta = (nb - na) / (2.0 * c);
                        double tt = (zeta >= 0.0 ? 1.0 : -1.0) / (fabs(zeta) + sqrt(1.0 + zeta * zeta));
                        double cs = 1.0 / sqrt(1.0 + tt * tt);
                        double sn = cs * tt;
                        #pragma unroll
                        for (int j = 0; j < 8; ++j) {
                            double nax = cs * va[j].x - sn * vb[j].x;
                            double nay = cs * va[j].y - sn * vb[j].y;
                            double nbx = sn * va[j].x + cs * vb[j].x;
                            double nby = sn * va[j].y + cs * vb[j].y;
                            gA[j * 8 + s8] = make_double2(nax, nay);
                            gB[j * 8 + s8] = make_double2(nbx, nby);
                        }
                        if (s8 == 0) {
                            norms2[ca] = fmax(na - tt * c, 0.0);
                            norms2[cb] = nb + tt * c;
                        }
                    }
                }
                __syncthreads();
            }
        }
        // ---------- in-place convert f64 [130] -> f32 [132] (two-pass) ----------
        {
            float tmp[32];
            int idx = 0;
            for (int e = t; e < M * M; e += 512) tmp[idx++] = (float)G[(e >> 7) * 130 + (e & 127)];
            __syncthreads();
            idx = 0;
            for (int e = t; e < M * M; e += 512) G32[(e >> 7) * 132 + (e & 127)] = tmp[idx++];
            __syncthreads();
        }
        // ---------- phase 2: f32 sweeps ----------
        for (; sweep < NSWEEP; ++sweep) {
            if (t < 64) {
                double mm = fmax(norms2[t], norms2[t + 64]);
                for (int off = 32; off > 0; off >>= 1) mm = fmax(mm, __shfl_down(mm, off));
                if (t == 0) {
                    maxn2s = mm;
                    done = (sweep > 0 && anyrot == 0);
                    anyrot = 0;
                }
            }
            __syncthreads();
            if (done) break;
            double kc = maxn2s * (RCOND * RCOND);
            for (int r = 0; r < NROUND; ++r) {
                int ca, cb;
                if (grp == 0) { ca = 127; cb = r; }
                else { ca = (r + grp) % 127; cb = (r + 127 - grp) % 127; }
                double na = norms2[ca], nb = norms2[cb];
                if (na + nb >= kc) {
                    float4* gA = (float4*)(G32 + ca * 132);
                    float4* gB = (float4*)(G32 + cb * 132);
                    float4 va[4], vb[4];
                    #pragma unroll
                    for (int j = 0; j < 4; ++j) va[j] = gA[j * 8 + s8];
                    #pragma unroll
                    for (int j = 0; j < 4; ++j) vb[j] = gB[j * 8 + s8];
                    float c32 = 0.f;
                    #pragma unroll
                    for (int j = 0; j < 4; ++j)
                        c32 += va[j].x * vb[j].x + va[j].y * vb[j].y
                             + va[j].z * vb[j].z + va[j].w * vb[j].w;
                    c32 += __shfl_xor(c32, 1); c32 += __shfl_xor(c32, 2); c32 += __shfl_xor(c32, 4);
                    double c = (double)c32;
                    if (c * c > 1e-14 * na * nb) {   // below: c is f32 noise, rotation pointless
                        if (na > kc && nb > kc && c * c > 1.6e-11 * na * nb) anyrot = 1;
                        double zeta = (nb - na) / (2.0 * c);
                        double tt = (zeta >= 0.0 ? 1.0 : -1.0) / (fabs(zeta) + sqrt(1.0 + zeta * zeta));
                        double cs = 1.0 / sqrt(1.0 + tt * tt);
                        double sn = cs * tt;
                        float csf = (float)cs, snf = (float)sn;
                        #pragma unroll
                        for (int j = 0; j < 4; ++j) {
                            float4 a = va[j], b = vb[j];
                            gA[j * 8 + s8] = make_float4(csf * a.x - snf * b.x, csf * a.y - snf * b.y,
                                                         csf * a.z - snf * b.z, csf * a.w - snf * b.w);
                            gB[j * 8 + s8] = make_float4(snf * a.x + csf * b.x, snf * a.y + csf * b.y,
                                                         snf * a.z + csf * b.z, snf * a.w + csf * b.w);
                        }
                        if (s8 == 0) {
                            norms2[ca] = fmax(na - tt * c, 0.0);
                            norms2[cb] = nb + tt * c;
                        }
                    }
                }
                __syncthreads();
            }
        }
        // ---------- exact norms (f64 from f32 data) + truncation + W = u / sigma^2 ----------
        {
            int col = t >> 2, qd = t & 3;
            double s = 0.0;
            #pragma unroll 8
            for (int x = qd * 32; x < qd * 32 + 32; ++x) { double vv = (double)G32[col * 132 + x]; s += vv * vv; }
            s += __shfl_xor(s, 1); s += __shfl_xor(s, 2);
            if (qd == 0) norms2[col] = s;
        }
        __syncthreads();
        if (t < 64) {
            double mm = fmax(norms2[t], norms2[t + 64]);
            for (int off = 32; off > 0; off >>= 1) mm = fmax(mm, __shfl_down(mm, off));
            if (t == 0) maxn2s = mm;
        }
        __syncthreads();
        double cut2 = maxn2s * (RCOND * RCOND);
        for (int e = t; e < M * M; e += 512) {
            int cc = e >> 7, rr = e & 127;
            double n2 = norms2[cc];
            Wcol[(size_t)head * M * M + e] = (n2 > cut2) ? (double)G32[cc * 132 + rr] / n2 : 0.0;
        }
    } else {
        // ======================= B@v (tiled GEMM) =======================
        int bb = blockIdx.x - BH;        // 0..255
        int head = bb >> 2;
        int chunk = bb & 3;
        float* F = (float*)ldsd;
        float* qls = F;                  // [128][68]  8704 f32
        float* kls = F + 8704;           // [64][68]   4352
        float* vls = F + 13056;          // [64][68]   4352
        float* Zl  = F + 17408;          // [64][132]  8448  (f32 E-tile, [key][m])
        // stage ql once
        {
            const float4* qg = (const float4*)(qlf32 + (size_t)head * M * DHEAD);
            for (int e = t; e < 2048; e += 512) {
                int m = e >> 4, dq = e & 15;
                *(float4*)&qls[m * 68 + dq * 4] = qg[e];
            }
        }
        int mb = t >> 4, lo = t & 15;    // phase1: keys j*16+lo; phase2: (mb, db=lo)
        double acc64[16];                // [i 4m][4 d]
        double den64[4];
        #pragma unroll
        for (int i = 0; i < 16; ++i) acc64[i] = 0.0;
        #pragma unroll
        for (int i = 0; i < 4; ++i) den64[i] = 0.0;
        size_t keybase = (size_t)head * NSEQ + (size_t)chunk * KPB;
        for (int tt = 0; tt < NTILE; ++tt) {
            __syncthreads();             // previous phase2 done reading kls/vls/Zl
            const float4* kg = (const float4*)(k + (keybase + tt * TILE) * DHEAD);
            const float4* vg = (const float4*)(v + (keybase + tt * TILE) * DHEAD);
            for (int e = t; e < 1024; e += 512) {
                int key = e >> 4, dq = e & 15;
                *(float4*)&kls[key * 68 + dq * 4] = kg[e];
                *(float4*)&vls[key * 68 + dq * 4] = vg[e];
            }
            __syncthreads();
            // phase 1: z[4m][4k] logits + exp -> Zl ; keys = j*16+lo
            float z0[4], z1[4], z2[4], z3[4];
            #pragma unroll
            for (int j = 0; j < 4; ++j) { z0[j] = 0.f; z1[j] = 0.f; z2[j] = 0.f; z3[j] = 0.f; }
            for (int dc = 0; dc < DHEAD; dc += 4) {
                float4 qr[4], kr[4];
                #pragma unroll
                for (int i = 0; i < 4; ++i) qr[i] = *(const float4*)&qls[(mb * 4 + i) * 68 + dc];
                #pragma unroll
                for (int j = 0; j < 4; ++j) kr[j] = *(const float4*)&kls[(j * 16 + lo) * 68 + dc];
                #pragma unroll
                for (int j = 0; j < 4; ++j) {
                    z0[j] += qr[0].x * kr[j].x + qr[0].y * kr[j].y + qr[0].z * kr[j].z + qr[0].w * kr[j].w;
                    z1[j] += qr[1].x * kr[j].x + qr[1].y * kr[j].y + qr[1].z * kr[j].z + qr[1].w * kr[j].w;
                    z2[j] += qr[2].x * kr[j].x + qr[2].y * kr[j].y + qr[2].z * kr[j].z + qr[2].w * kr[j].w;
                    z3[j] += qr[3].x * kr[j].x + qr[3].y * kr[j].y + qr[3].z * kr[j].z + qr[3].w * kr[j].w;
                }
            }
            #pragma unroll
            for (int j = 0; j < 4; ++j) {
                float4 ej;
                ej.x = __expf(z0[j]); ej.y = __expf(z1[j]);
                ej.z = __expf(z2[j]); ej.w = __expf(z3[j]);
                *(float4*)&Zl[(j * 16 + lo) * 132 + mb * 4] = ej;
            }
            __syncthreads();
            // phase 2: acc[4m][4d] += E[4m][key] * V[key][4d]; f32 tile acc, f64 flush
            float4 a32[4];
            #pragma unroll
            for (int i = 0; i < 4; ++i) a32[i] = make_float4(0.f, 0.f, 0.f, 0.f);
            float den32[4] = {0.f, 0.f, 0.f, 0.f};
            for (int key = 0; key < TILE; ++key) {
                float4 vv = *(const float4*)&vls[key * 68 + lo * 4];
                float4 ee = *(const float4*)&Zl[key * 132 + mb * 4];
                a32[0].x += ee.x * vv.x; a32[0].y += ee.x * vv.y; a32[0].z += ee.x * vv.z; a32[0].w += ee.x * vv.w;
                a32[1].x += ee.y * vv.x; a32[1].y += ee.y * vv.y; a32[1].z += ee.y * vv.z; a32[1].w += ee.y * vv.w;
                a32[2].x += ee.z * vv.x; a32[2].y += ee.z * vv.y; a32[2].z += ee.z * vv.z; a32[2].w += ee.z * vv.w;
                a32[3].x += ee.w * vv.x; a32[3].y += ee.w * vv.y; a32[3].z += ee.w * vv.z; a32[3].w += ee.w * vv.w;
                if (lo == 0) { den32[0] += ee.x; den32[1] += ee.y; den32[2] += ee.z; den32[3] += ee.w; }
            }
            #pragma unroll
            for (int i = 0; i < 4; ++i) {
                acc64[i * 4 + 0] += (double)a32[i].x;
                acc64[i * 4 + 1] += (double)a32[i].y;
                acc64[i * 4 + 2] += (double)a32[i].z;
                acc64[i * 4 + 3] += (double)a32[i].w;
            }
            if (lo == 0) {
                #pragma unroll
                for (int i = 0; i < 4; ++i) den64[i] += (double)den32[i];
            }
        }
        // write partials
        #pragma unroll
        for (int i = 0; i < 4; ++i) {
            size_t ob = (((size_t)head * NCB + chunk) * M + mb * 4 + i) * DHEAD + lo * 4;
            *(double2*)&numd[ob]     = make_double2(acc64[i * 4 + 0], acc64[i * 4 + 1]);
            *(double2*)&numd[ob + 2] = make_double2(acc64[i * 4 + 2], acc64[i * 4 + 3]);
        }
        if (lo == 0) {
            #pragma unroll
            for (int i = 0; i < 4; ++i)
                dend[((size_t)head * NCB + chunk) * M + mb * 4 + i] = den64[i];
        }
    }
}

// ---------------- Kernel E: fused  Bv reduce -> W^T -> W -> S^T  (f64, ABv out f32) ----
__global__ __launch_bounds__(512) void apply_kernel(const double* __restrict__ numd,
                                                    const double* __restrict__ dend,
                                                    const double* __restrict__ Wcol,
                                                    const double* __restrict__ Sg,
                                                    float* __restrict__ ABvf32) {
    extern __shared__ double lds[];
    double* A_ = lds;                 // [128][66]
    double* B_ = lds + M * 66;
    __shared__ double dsum[M];
    int head = blockIdx.x;
    int t = threadIdx.x;
    if (t < M) {
        double s = 0.0;
        #pragma unroll
        for (int c = 0; c < NCB; ++c) s += dend[((size_t)head * NCB + c) * M + t];
        dsum[t] = s;
    }
    __syncthreads();
    for (int e = t; e < M * DHEAD; e += 512) {
        int mm = e >> 6;
        double s = 0.0;
        #pragma unroll
        for (int c = 0; c < NCB; ++c) s += numd[((size_t)head * NCB + c) * (M * DHEAD) + e];
        A_[mm * 66 + (e & 63)] = s / dsum[mm];
    }
    __syncthreads();
    int i = t >> 3, qd = t & 7;
    const double* Wb = Wcol + (size_t)head * M * M;
    const double* Sb = Sg + (size_t)head * M * M;
    {   // stage 1: B = W^T A
        double a0[8], a1[8];
        #pragma unroll
        for (int d = 0; d < 8; ++d) { a0[d] = 0.0; a1[d] = 0.0; }
        for (int r = 0; r < M; ++r) {
            double m0 = Wb[(size_t)i * M + r];
            double m1 = Wb[(size_t)(i + 64) * M + r];
            #pragma unroll
            for (int d = 0; d < 8; ++d) {
                double xv = A_[r * 66 + qd * 8 + d];
                a0[d] += m0 * xv; a1[d] += m1 * xv;
            }
        }
        #pragma unroll
        for (int d = 0; d < 8; ++d) {
            B_[i * 66 + qd * 8 + d] = a0[d];
            B_[(i + 64) * 66 + qd * 8 + d] = a1[d];
        }
    }
    __syncthreads();
    {   // stage 2: A = W B
        double a0[8], a1[8];
        #pragma unroll
        for (int d = 0; d < 8; ++d) { a0[d] = 0.0; a1[d] = 0.0; }
        for (int r = 0; r < M; ++r) {
            double m0 = Wb[(size_t)r * M + i];
            double m1 = Wb[(size_t)r * M + i + 64];
            #pragma unroll
            for (int d = 0; d < 8; ++d) {
                double xv = B_[r * 66 + qd * 8 + d];
                a0[d] += m0 * xv; a1[d] += m1 * xv;
            }
        }
        #pragma unroll
        for (int d = 0; d < 8; ++d) {
            A_[i * 66 + qd * 8 + d] = a0[d];
            A_[(i + 64) * 66 + qd * 8 + d] = a1[d];
        }
    }
    __syncthreads();
    {   // stage 3: ABv = S^T A
        double a0[8], a1[8];
        #pragma unroll
        for (int d = 0; d < 8; ++d) { a0[d] = 0.0; a1[d] = 0.0; }
        for (int r = 0; r < M; ++r) {
            double m0 = Sb[(size_t)i * M + r];
            double m1 = Sb[(size_t)(i + 64) * M + r];
            #pragma unroll
            for (int d = 0; d < 8; ++d) {
                double xv = A_[r * 66 + qd * 8 + d];
                a0[d] += m0 * xv; a1[d] += m1 * xv;
            }
        }
        float* ob = ABvf32 + (size_t)head * M * DHEAD;
        #pragma unroll
        for (int d = 0; d < 8; ++d) {
            ob[i * DHEAD + qd * 8 + d] = (float)a0[d];
            ob[(i + 64) * DHEAD + qd * 8 + d] = (float)a1[d];
        }
    }
}

// ---------------- Kernel F: out = softmax(q @ kl^T) @ ABv  (f32, 2-row tiling) --------
__global__ __launch_bounds__(512) void out_kernel(const float* __restrict__ q,
                                                  const float* __restrict__ klf32,
                                                  const float* __restrict__ ABvf32,
                                                  float* __restrict__ out) {
    __shared__ float kls[M * DHEAD];
    __shared__ float avs[M * DHEAD];
    int head = blockIdx.x >> 4;
    int tile = blockIdx.x & 15;
    int t = threadIdx.x;
    for (int e = t; e < M * DHEAD; e += 512) {
        kls[e] = klf32[(size_t)head * M * DHEAD + e];
        avs[e] = ABvf32[(size_t)head * M * DHEAD + e];
    }
    __syncthreads();
    int rl = t >> 1, h = t & 1;
    size_t row0 = (size_t)head * NSEQ + (size_t)tile * 512 + rl;
    size_t row1 = row0 + 256;
    const float4* qr0 = (const float4*)(q + row0 * DHEAD + h * 32);
    const float4* qr1 = (const float4*)(q + row1 * DHEAD + h * 32);
    float4 qa[8], qb[8];
    #pragma unroll
    for (int c = 0; c < 8; ++c) {
        float4 x = qr0[c];
        x.x *= 0.125f; x.y *= 0.125f; x.z *= 0.125f; x.w *= 0.125f;
        qa[c] = x;
        float4 y = qr1[c];
        y.x *= 0.125f; y.y *= 0.125f; y.z *= 0.125f; y.w *= 0.125f;
        qb[c] = y;
    }
    float acc0[32], acc1[32];
    #pragma unroll
    for (int d = 0; d < 32; ++d) { acc0[d] = 0.f; acc1[d] = 0.f; }
    float d0 = 0.f, d1 = 0.f;
    for (int mm = 0; mm < M; ++mm) {
        const float4* kr = (const float4*)(kls + mm * DHEAD + h * 32);
        float z0 = 0.f, z1 = 0.f;
        #pragma unroll
        for (int c = 0; c < 8; ++c) {
            float4 kk = kr[c];
            z0 += qa[c].x * kk.x + qa[c].y * kk.y + qa[c].z * kk.z + qa[c].w * kk.w;
            z1 += qb[c].x * kk.x + qb[c].y * kk.y + qb[c].z * kk.z + qb[c].w * kk.w;
        }
        z0 += __shfl_xor(z0, 1);
        z1 += __shfl_xor(z1, 1);
        float e0 = __expf(z0), e1 = __expf(z1);
        d0 += e0; d1 += e1;
        const float4* ar = (const float4*)(avs + mm * DHEAD + h * 32);
        #pragma unroll
        for (int c = 0; c < 8; ++c) {
            float4 av = ar[c];
            acc0[4 * c]     += e0 * av.x; acc0[4 * c + 1] += e0 * av.y;
            acc0[4 * c + 2] += e0 * av.z; acc0[4 * c + 3] += e0 * av.w;
            acc1[4 * c]     += e1 * av.x; acc1[4 * c + 1] += e1 * av.y;
            acc1[4 * c + 2] += e1 * av.z; acc1[4 * c + 3] += e1 * av.w;
        }
    }
    float i0 = 1.f / d0, i1 = 1.f / d1;
    float* o0 = out + row0 * DHEAD + h * 32;
    float* o1 = out + row1 * DHEAD + h * 32;
    #pragma unroll
    for (int d = 0; d < 32; ++d) { o0[d] = acc0[d] * i0; o1[d] = acc1[d] * i1; }
}

extern "C" void kernel_launch(void* const* d_in, const int* in_sizes, int n_in,
                              void* d_out, int out_size, void* d_ws, size_t ws_size,
                              hipStream_t stream) {
    const float* q = (const float*)d_in[0];
    const float* k = (const float*)d_in[1];
    const float* v = (const float*)d_in[2];
    float* out = (float*)d_out;
    char* ws = (char*)d_ws;
    // ws map. ql64/kl64 [0,8M) die after s_kernel; numd [0,16M) written by fused.
    double* ql64  = (double*)(ws + 0);            //  4 MB
    double* kl64  = (double*)(ws + 4194304);      //  4 MB
    double* numd  = (double*)(ws + 0);            // 16 MB (after s_kernel)
    double* dend  = (double*)(ws + 33554432);     //  256 KB
    float*  qlf32 = (float*)(ws + 34078720);      //  2 MB
    float*  klf32 = (float*)(ws + 36175872);      //  2 MB
    double* Sg    = (double*)(ws + 38273024);     //  8 MB (S col-major)
    double* Wcol  = (double*)(ws + 46661632);     //  8 MB
    float*  ABvf32= (float*)(ws + 55050240);      //  2 MB

    lm_kernel<<<16384, 64, 0, stream>>>(q, k, ql64, kl64, qlf32, klf32);
    s_kernel<<<BH, 512, 2 * M * DHEAD * 8, stream>>>(ql64, kl64, Sg);
    fused_kernel<<<BH + 256, 512, 133120, stream>>>(Sg, Wcol, k, v, qlf32, numd, dend);
    apply_kernel<<<BH, 512, 2 * M * 66 * 8, stream>>>(numd, dend, Wcol, Sg, ABvf32);
    out_kernel<<<BH * 16, 512, 0, stream>>>(q, klf32, ABvf32, out);
}